// Round 8
// baseline (159.029 us; speedup 1.0000x reference)
//
#include <hip/hip_runtime.h>

typedef unsigned short u16;
typedef unsigned int u32;
typedef float f32x4 __attribute__((ext_vector_type(4)));
typedef float f32x2 __attribute__((ext_vector_type(2)));
typedef unsigned int u32x2 __attribute__((ext_vector_type(2)));
typedef __bf16 bf16x8 __attribute__((ext_vector_type(8)));
typedef __bf16 bf16x4 __attribute__((ext_vector_type(4)));

#define LAMBDA_INIT_F 0.7836057665316245f
#define ONE_MINUS_LI  0.2163942334683755f
#define THR_LOG2 11.0f
// 0.125 * log2(e): fold softmax base-2 conversion into Q scaling
#define Q_SCALE 0.18033688011112042f

__device__ __forceinline__ u16 f2b(float f) {
  union { float f; u32 u; } x; x.f = f;
  u32 r = x.u + 0x7fffu + ((x.u >> 16) & 1u);
  return (u16)(r >> 16);
}

__device__ __forceinline__ f32x4 mfma16(bf16x8 a, bf16x8 b, f32x4 c) {
  return __builtin_amdgcn_mfma_f32_16x16x32_bf16(a, b, c, 0, 0, 0);
}

__device__ __forceinline__ float fexp2(float x) { return __builtin_amdgcn_exp2f(x); }

// async global->LDS, 16B per lane; LDS dest must be linear in lane order
__device__ __forceinline__ void gll16(const void* gp, void* lp) {
  __builtin_amdgcn_global_load_lds((__attribute__((address_space(1))) void*)(gp),
                                   (__attribute__((address_space(3))) void*)(lp),
                                   16, 0, 0);
}

// ------------- tiled transpose+cast body: f32 [R][C] -> bf16 [C][R] -----------
__device__ __forceinline__ void trans_body2(const float* __restrict__ in,
                                            u16* __restrict__ out, int R, int C,
                                            int bxb, int byb) {
  __shared__ float tile[32][33];
  int bx = bxb * 32;  // col base
  int by = byb * 32;  // row base
  int tx = threadIdx.x & 31, ty = threadIdx.x >> 5;
#pragma unroll
  for (int i = 0; i < 32; i += 8)
    tile[ty + i][tx] = in[(size_t)(by + ty + i) * C + bx + tx];
  __syncthreads();
#pragma unroll
  for (int i = 0; i < 32; i += 8)
    out[(size_t)(bx + ty + i) * R + by + tx] = f2b(tile[tx][ty + i]);
}

// --- fused prep: cast q/k/v -> bf16, rope cos/sin table, 4 weight transposes --
// grid 1D: [0,6144) cast, [6144,6400) table, [6400,18688) wtrans
__global__ __launch_bounds__(256) void prep_kernel(
    const float* __restrict__ q, const float* __restrict__ k, const float* __restrict__ v,
    u16* __restrict__ qb, u16* __restrict__ kb, u16* __restrict__ vb,
    f32x2* __restrict__ tbl,
    const float* __restrict__ Wq, u16* __restrict__ WqT,
    const float* __restrict__ Wk, u16* __restrict__ WkT,
    const float* __restrict__ Wv, u16* __restrict__ WvT,
    const float* __restrict__ Wo, u16* __restrict__ WoT) {
  int bid = blockIdx.x;
  if (bid < 6144) {
    int seg = bid >> 11;
    int i = (bid & 2047) * 256 + threadIdx.x;
    const float* in = seg == 0 ? q : (seg == 1 ? k : v);
    u16* out = seg == 0 ? qb : (seg == 1 ? kb : vb);
    const f32x4* p = (const f32x4*)(in + (size_t)i * 8);
    f32x4 a = p[0], b = p[1];
    union { u16 u[8]; f32x4 v; } o;
#pragma unroll
    for (int j = 0; j < 4; ++j) { o.u[j] = f2b(a[j]); o.u[4 + j] = f2b(b[j]); }
    *(f32x4*)(out + (size_t)i * 8) = o.v;
    return;
  }
  if (bid < 6400) {
    int idx = (bid - 6144) * 256 + threadIdx.x;  // t*32 + j
    int t = idx >> 5, j = idx & 31;
    float theta = (float)j * (1.0f / 32.0f);
    float denom = expf(theta * 9.210340371976184f);  // 10000^theta
    float invf = 1.0f / (denom + 1e-8f);
    float ang = (float)t * invf;
    tbl[idx] = (f32x2){cosf(ang), sinf(ang)};
    return;
  }
  int w = bid - 6400;
  if (w < 4096)      trans_body2(Wq, WqT, 2048, 2048, w & 63, w >> 6);
  else if (w < 6144) { w -= 4096; trans_body2(Wk, WkT, 2048, 1024, w & 31, w >> 5); }
  else if (w < 8192) { w -= 6144; trans_body2(Wv, WvT, 2048, 1024, w & 31, w >> 5); }
  else               { w -= 8192; trans_body2(Wo, WoT, 2048, 2048, w & 63, w >> 6); }
}

// ---------------- GEMM body: 128x128 tile, BK=64, fused epilogues -------------
// MODE 0: plain f32 C[M][N]
// MODE 1: RoPE (interleaved pairs via shfl_xor(1), table cos/sin) -> bf16
//         head-major Oh[ncol>>6][t][64]; even lanes store packed u32 pairs.
// MODE 2: V permuted transpose -> bf16 Vt[dv][2048]; within each 32-key block
//         position p = 8g + 4(i&1) + r (r-contiguous -> one 8B store per quad).
template <int MODE>
__device__ __forceinline__ void gemm_body(u16* As, u16* Bs,
                                          const u16* __restrict__ A,
                                          const u16* __restrict__ Bt,
                                          void* __restrict__ Cout,
                                          const f32x2* __restrict__ tbl,
                                          float scale,
                                          int N, int K, int bx, int by) {
  const int tid = threadIdx.x;
  const int lane = tid & 63;
  const int wave = tid >> 6;
  const int m0 = by * 128;
  const int n0 = bx * 128;
  const int wm = (wave >> 1) * 64;
  const int wn = (wave & 1) * 64;
  const int g = lane >> 4, c = lane & 15;

  f32x4 acc[4][4];
#pragma unroll
  for (int i = 0; i < 4; ++i)
#pragma unroll
    for (int j = 0; j < 4; ++j) acc[i][j] = (f32x4){0.f, 0.f, 0.f, 0.f};

  for (int k0 = 0; k0 < K; k0 += 64) {
    __syncthreads();
#pragma unroll
    for (int it = 0; it < 4; ++it) {
      int gi = it * 256 + tid;
      int R = gi >> 3;
      int lg = (gi & 7) ^ (R & 7);
      gll16(A + (size_t)(m0 + R) * K + k0 + lg * 8, As + gi * 8);
      gll16(Bt + (size_t)(n0 + R) * K + k0 + lg * 8, Bs + gi * 8);
    }
    __syncthreads();
#pragma unroll
    for (int kk = 0; kk < 2; ++kk) {
      bf16x8 af[4], bf[4];
#pragma unroll
      for (int i = 0; i < 4; ++i) {
        int ph = ((kk * 4 + g) ^ (c & 7)) * 8;
        af[i] = *(const bf16x8*)&As[(wm + i * 16 + c) * 64 + ph];
        bf[i] = *(const bf16x8*)&Bs[(wn + i * 16 + c) * 64 + ph];
      }
#pragma unroll
      for (int i = 0; i < 4; ++i)
#pragma unroll
        for (int j = 0; j < 4; ++j) acc[i][j] = mfma16(af[i], bf[j], acc[i][j]);
    }
  }

  if constexpr (MODE == 0) {
    float* C = (float*)Cout;
#pragma unroll
    for (int i = 0; i < 4; ++i)
#pragma unroll
      for (int j = 0; j < 4; ++j) {
        int mrow = m0 + wm + i * 16 + g * 4;
        int ncol = n0 + wn + j * 16 + c;
#pragma unroll
        for (int r = 0; r < 4; ++r) C[(size_t)(mrow + r) * N + ncol] = acc[i][j][r];
      }
  } else if constexpr (MODE == 1) {
    u16* Oh = (u16*)Cout;
    const bool even = (c & 1) == 0;
#pragma unroll
    for (int i = 0; i < 4; ++i)
#pragma unroll
      for (int j = 0; j < 4; ++j) {
        int mrow = m0 + wm + i * 16 + g * 4;
        int ncol = n0 + wn + j * 16 + c;
        int hh = ncol >> 6;
        int d = ncol & 63;
        int jd = d >> 1;
        f32x4 own = acc[i][j];
        f32x4 part;
#pragma unroll
        for (int r = 0; r < 4; ++r) part[r] = __shfl_xor(own[r], 1);
        if (even) {
#pragma unroll
          for (int r = 0; r < 4; ++r) {
            f32x2 cs = tbl[(mrow + r) * 32 + jd];
            float o1 = (own[r] * cs[0] - part[r] * cs[1]) * scale;
            float o2 = (own[r] * cs[1] + part[r] * cs[0]) * scale;
            u32 pk = (u32)f2b(o1) | ((u32)f2b(o2) << 16);
            *(u32*)&Oh[((size_t)hh * 2048 + mrow + r) * 64 + d] = pk;
          }
        }
      }
  } else {
    u16* Vt = (u16*)Cout;
#pragma unroll
    for (int i = 0; i < 4; ++i)
#pragma unroll
      for (int j = 0; j < 4; ++j) {
        int ncol = n0 + wn + j * 16 + c;              // dv
        int tblk = (m0 + wm + i * 16) >> 5;           // 32-key block
        int p0 = 8 * g + 4 * (i & 1);                 // permuted base, +r contiguous
        u32x2 pk;
        pk[0] = (u32)f2b(acc[i][j][0]) | ((u32)f2b(acc[i][j][1]) << 16);
        pk[1] = (u32)f2b(acc[i][j][2]) | ((u32)f2b(acc[i][j][3]) << 16);
        *(u32x2*)&Vt[(size_t)ncol * 2048 + tblk * 32 + p0] = pk;
      }
  }
}

// fused q/k/v projections + RoPE + V-transpose epilogues: 512 blocks (2/CU)
__global__ __launch_bounds__(256, 2) void gemm_qkv_kernel(
    const u16* __restrict__ qb, const u16* __restrict__ WqT, u16* __restrict__ Qh,
    const u16* __restrict__ kb, const u16* __restrict__ WkT, u16* __restrict__ Kh,
    const u16* __restrict__ vb, const u16* __restrict__ WvT, u16* __restrict__ Vt,
    const f32x2* __restrict__ tbl) {
  __shared__ u16 As[128 * 64];
  __shared__ u16 Bs[128 * 64];
  // XCD-aware swizzle: 512 blocks, 64 consecutive work-ids per XCD
  int bid = ((blockIdx.x & 7) << 6) | (blockIdx.x >> 3);
  if (bid < 256) {
    gemm_body<1>(As, Bs, qb, WqT, Qh, tbl, Q_SCALE, 2048, 2048, bid & 15, bid >> 4);
  } else if (bid < 384) {
    int t = bid - 256;
    gemm_body<1>(As, Bs, kb, WkT, Kh, tbl, 1.0f, 1024, 2048, t & 7, t >> 3);
  } else {
    int t = bid - 384;
    gemm_body<2>(As, Bs, vb, WvT, Vt, tbl, 1.0f, 1024, 2048, t & 7, t >> 3);
  }
}

__global__ __launch_bounds__(256, 2) void gemm_one_kernel(const u16* __restrict__ A,
                                                          const u16* __restrict__ Bt,
                                                          float* __restrict__ C) {
  __shared__ u16 As[128 * 64];
  __shared__ u16 Bs[128 * 64];
  int bid = ((blockIdx.x & 7) << 5) | (blockIdx.x >> 3);  // 256 blocks
  gemm_body<0>(As, Bs, A, Bt, C, nullptr, 1.0f, 2048, 2048, bid & 15, bid >> 4);
}

// ---------------- fused differential flash attention --------------------------
// R7 TILE math (permuted Vt -> single b128 PV fragments, conflicts 0) on the
// 4-wave/512-block grid (R5 shape): 2 blocks/CU -> 4 waves/SIMD for latency
// hiding (R7's 8-wave/256-block shape left CUs at 2 waves/SIMD, ~60% idle).
__global__ __launch_bounds__(256, 2) void attn_kernel(const u16* __restrict__ Qb,
                                                      const u16* __restrict__ Kb,
                                                      const u16* __restrict__ Vt,
                                                      u16* __restrict__ AO,
                                                      const float* __restrict__ lq1,
                                                      const float* __restrict__ lk1,
                                                      const float* __restrict__ lq2,
                                                      const float* __restrict__ lk2,
                                                      const float* __restrict__ subln) {
  // XCD swizzle: 64 consecutive work-ids (2 heads) per XCD's L2
  const int b = ((blockIdx.x & 7) << 6) | (blockIdx.x >> 3);
  const int h = b >> 5;
  const int tid = threadIdx.x;
  const int wave = tid >> 6;
  const int lane = tid & 63;
  const int t0 = ((b & 31) * 4 + wave) * 16;
  const int g = lane >> 4, c = lane & 15;
  const int c7 = c & 7;

  __shared__ u16 smem[24576];  // 48KB: K0@0 K1@4096 V0@8192 V1@16384

  const u16* Kh = Kb + (size_t)h * 2048 * 64;
  const u16* Vh = Vt + (size_t)(h >> 1) * 128 * 2048;

  // lambda (wave-parallel)
  float myl1 = lq1[lane] * lk1[lane];
  float myl2 = lq2[lane] * lk2[lane];
#pragma unroll
  for (int off = 32; off; off >>= 1) {
    myl1 += __shfl_xor(myl1, off);
    myl2 += __shfl_xor(myl2, off);
  }
  const float lambda_full = expf(myl1) - expf(myl2) + LAMBDA_INIT_F;

  // Q fragments (B-operand: col = q-row = c, natural d-slots)
  bf16x8 qf[2][2];
#pragma unroll
  for (int e = 0; e < 2; ++e)
#pragma unroll
    for (int d = 0; d < 2; ++d)
      qf[e][d] = *(const bf16x8*)(Qb + ((size_t)(2 * h + e) * 2048 + t0 + c) * 64 + d * 32 + g * 8);

  // loop-invariant LDS read bases (u16-elem units); shared by K and V reads
  const int kb0 = c * 64 + ((g ^ c7) * 8);
  const int kb1 = kb0 ^ 32;

  // per-thread stage source bases (granule-XOR pre-swizzled)
  const u16* ksrc0;
  const u16* ksrc1;
  const u16* vsrc0;
  const u16* vsrc1;
  const u16* vsrc2;
  const u16* vsrc3;
  { int gi = tid;       int R = gi >> 3; ksrc0 = Kh + R * 64 + ((gi & 7) ^ (R & 7)) * 8; }
  { int gi = 256 + tid; int R = gi >> 3; ksrc1 = Kh + R * 64 + ((gi & 7) ^ (R & 7)) * 8; }
  { int gi = tid;       int R = gi >> 3; vsrc0 = Vh + (size_t)R * 2048 + ((gi & 7) ^ (R & 7)) * 8; }
  { int gi = 256 + tid; int R = gi >> 3; vsrc1 = Vh + (size_t)R * 2048 + ((gi & 7) ^ (R & 7)) * 8; }
  { int gi = 512 + tid; int R = gi >> 3; vsrc2 = Vh + (size_t)R * 2048 + ((gi & 7) ^ (R & 7)) * 8; }
  { int gi = 768 + tid; int R = gi >> 3; vsrc3 = Vh + (size_t)R * 2048 + ((gi & 7) ^ (R & 7)) * 8; }

  f32x4 O[2][8];
#pragma unroll
  for (int e = 0; e < 2; ++e)
#pragma unroll
    for (int f = 0; f < 8; ++f) O[e][f] = (f32x4){0.f, 0.f, 0.f, 0.f};
  float m0 = -1e30f, m1 = -1e30f, ls0 = 0.f, ls1 = 0.f;

#define STAGE(kOff, vOff, s0)                                         \
  do {                                                                \
    gll16(ksrc0 + (size_t)(s0) * 64, smem + (kOff) + tid * 8);        \
    gll16(ksrc1 + (size_t)(s0) * 64, smem + (kOff) + 2048 + tid * 8); \
    gll16(vsrc0 + (s0), smem + (vOff) + tid * 8);                     \
    gll16(vsrc1 + (s0), smem + (vOff) + 2048 + tid * 8);              \
    gll16(vsrc2 + (s0), smem + (vOff) + 4096 + tid * 8);              \
    gll16(vsrc3 + (s0), smem + (vOff) + 6144 + tid * 8);              \
  } while (0)

#define TILE(kOff, vOff)                                                      \
  do {                                                                        \
    bf16x8 kf[4][2];                                                          \
    _Pragma("unroll") for (int sf = 0; sf < 4; ++sf) {                        \
      kf[sf][0] = *(const bf16x8*)&smem[(kOff) + kb0 + sf * 1024];            \
      kf[sf][1] = *(const bf16x8*)&smem[(kOff) + kb1 + sf * 1024];            \
    }                                                                         \
    f32x4 sa[2][4];                                                           \
    _Pragma("unroll") for (int e = 0; e < 2; ++e)                             \
      _Pragma("unroll") for (int sf = 0; sf < 4; ++sf) {                      \
        f32x4 z = (f32x4){0.f, 0.f, 0.f, 0.f};                                \
        z = mfma16(kf[sf][0], qf[e][0], z);                                   \
        z = mfma16(kf[sf][1], qf[e][1], z);                                   \
        sa[e][sf] = z;                                                        \
      }                                                                       \
    bf16x8 vv0[8];                                                            \
    _Pragma("unroll") for (int f = 0; f < 8; ++f)                             \
      vv0[f] = *(const bf16x8*)&smem[(vOff) + kb0 + f * 1024];                \
    bf16x8 paf[2][2];                                                         \
    _Pragma("unroll") for (int e = 0; e < 2; ++e) {                           \
      float& m_e = e ? m1 : m0;                                               \
      float& ls_e = e ? ls1 : ls0;                                            \
      float mx = sa[e][0][0];                                                 \
      _Pragma("unroll") for (int sf = 0; sf < 4; ++sf)                        \
        _Pragma("unroll") for (int r = 0; r < 4; ++r)                         \
          mx = fmaxf(mx, sa[e][sf][r]);                                       \
      mx = fmaxf(mx, __shfl_xor(mx, 16));                                     \
      mx = fmaxf(mx, __shfl_xor(mx, 32));                                     \
      if (__any(mx > m_e + THR_LOG2)) {                                       \
        float mn = fmaxf(m_e, mx);                                            \
        float sc = fexp2(m_e - mn);                                           \
        m_e = mn;                                                             \
        ls_e *= sc;                                                           \
        float scr[4];                                                         \
        _Pragma("unroll") for (int r = 0; r < 4; ++r) scr[r] = __shfl(sc, g * 4 + r); \
        _Pragma("unroll") for (int ff = 0; ff < 8; ++ff)                      \
          _Pragma("unroll") for (int r = 0; r < 4; ++r) O[e][ff][r] *= scr[r]; \
      }                                                                       \
      float p[4][4];                                                          \
      float sum = 0.f;                                                        \
      _Pragma("unroll") for (int sf = 0; sf < 4; ++sf)                        \
        _Pragma("unroll") for (int r = 0; r < 4; ++r) {                       \
          float pv = fexp2(sa[e][sf][r] - m_e);                               \
          p[sf][r] = pv;                                                      \
          sum += pv;                                                          \
        }                                                                     \
      sum += __shfl_xor(sum, 16);                                             \
      sum += __shfl_xor(sum, 32);                                             \
      ls_e += sum;                                                            \
      paf[e][0] = (bf16x8){(__bf16)p[0][0], (__bf16)p[0][1], (__bf16)p[0][2], (__bf16)p[0][3], \
                           (__bf16)p[1][0], (__bf16)p[1][1], (__bf16)p[1][2], (__bf16)p[1][3]}; \
      paf[e][1] = (bf16x8){(__bf16)p[2][0], (__bf16)p[2][1], (__bf16)p[2][2], (__bf16)p[2][3], \
                           (__bf16)p[3][0], (__bf16)p[3][1], (__bf16)p[3][2], (__bf16)p[3][3]}; \
    }                                                                         \
    __builtin_amdgcn_s_setprio(1);                                            \
    bf16x8 vv1[8];                                                            \
    _Pragma("unroll") for (int f = 0; f < 8; ++f)                             \
      vv1[f] = *(const bf16x8*)&smem[(vOff) + kb1 + f * 1024];                \
    _Pragma("unroll") for (int f = 0; f < 8; ++f) {                           \
      O[0][f] = mfma16(paf[0][0], vv0[f], O[0][f]);                           \
      O[1][f] = mfma16(paf[1][0], vv0[f], O[1][f]);                           \
    }                                                                         \
    _Pragma("unroll") for (int f = 0; f < 8; ++f) {                           \
      O[0][f] = mfma16(paf[0][1], vv1[f], O[0][f]);                           \
      O[1][f] = mfma16(paf[1][1], vv1[f], O[1][f]);                           \
    }                                                                         \
    __builtin_amdgcn_s_setprio(0);                                            \
  } while (0)

  STAGE(0, 8192, 0);

#pragma unroll 1
  for (int t = 0; t < 32; t += 2) {
    __syncthreads();  // vmcnt(0): buf0 staged; all waves done with buf1
    STAGE(4096, 16384, (t + 1) * 64);
    TILE(0, 8192);
    __syncthreads();  // buf1 staged; all waves done with buf0
    if (t < 30) STAGE(0, 8192, (t + 2) * 64);
    TILE(4096, 16384);
  }

  // epilogue: redistribute 1/ls from c-layout to (g,r)-layout
  float inv0 = 1.f / ls0, inv1 = 1.f / ls1;
  float i0[4], i1[4];
#pragma unroll
  for (int r = 0; r < 4; ++r) {
    i0[r] = __shfl(inv0, g * 4 + r);
    i1[r] = __shfl(inv1, g * 4 + r);
  }
  float res[8][4];
  float ss[4] = {0.f, 0.f, 0.f, 0.f};
#pragma unroll
  for (int f = 0; f < 8; ++f)
#pragma unroll
    for (int r = 0; r < 4; ++r) {
      float vv = O[0][f][r] * i0[r] - lambda_full * (O[1][f][r] * i1[r]);
      res[f][r] = vv;
      ss[r] += vv * vv;
    }
#pragma unroll
  for (int off = 1; off < 16; off <<= 1)
#pragma unroll
    for (int r = 0; r < 4; ++r) ss[r] += __shfl_xor(ss[r], off);
  float rms[4];
#pragma unroll
  for (int r = 0; r < 4; ++r)
    rms[r] = rsqrtf(ss[r] * (1.0f / 128.0f) + 1e-5f) * ONE_MINUS_LI;
  float w[8];
#pragma unroll
  for (int f = 0; f < 8; ++f) w[f] = subln[f * 16 + c];
#pragma unroll
  for (int f = 0; f < 8; ++f)
#pragma unroll
    for (int r = 0; r < 4; ++r)
      AO[(size_t)(t0 + g * 4 + r) * 2048 + h * 128 + f * 16 + c] = f2b(res[f][r] * rms[r] * w[f]);
}

// ------------------------------------------------------------------------------
extern "C" void kernel_launch(void* const* d_in, const int* in_sizes, int n_in,
                              void* d_out, int out_size, void* d_ws, size_t ws_size,
                              hipStream_t stream) {
  const float* q     = (const float*)d_in[0];
  const float* k     = (const float*)d_in[1];
  const float* v     = (const float*)d_in[2];
  const float* Wq    = (const float*)d_in[3];
  const float* Wk    = (const float*)d_in[4];
  const float* Wv    = (const float*)d_in[5];
  const float* Wout  = (const float*)d_in[6];
  const float* lq1   = (const float*)d_in[7];
  const float* lk1   = (const float*)d_in[8];
  const float* lq2   = (const float*)d_in[9];
  const float* lk2   = (const float*)d_in[10];
  const float* subln = (const float*)d_in[11];
  float* out = (float*)d_out;

  char* ws = (char*)d_ws;
  size_t off = 0;
  auto alloc = [&](size_t bytes) -> void* {
    void* p = ws + off;
    off += (bytes + 255) & ~(size_t)255;
    return p;
  };
  u16* qb  = (u16*)alloc(2048ull * 2048 * 2);
  u16* kb  = (u16*)alloc(2048ull * 2048 * 2);
  u16* vb  = (u16*)alloc(2048ull * 2048 * 2);
  u16* WqT = (u16*)alloc(2048ull * 2048 * 2);
  u16* WkT = (u16*)alloc(1024ull * 2048 * 2);
  u16* WvT = (u16*)alloc(1024ull * 2048 * 2);
  u16* WoT = (u16*)alloc(2048ull * 2048 * 2);
  f32x2* tbl = (f32x2*)alloc(2048ull * 32 * 8);
  u16* Qh  = (u16*)alloc(32ull * 2048 * 64 * 2);
  u16* Kh  = (u16*)alloc(16ull * 2048 * 64 * 2);
  u16* Vt  = (u16*)alloc(1024ull * 2048 * 2);
  u16* AO  = (u16*)alloc(2048ull * 2048 * 2);

  // 1. fused prep: cast q/k/v + rope table + all weight transposes (one launch)
  prep_kernel<<<18688, 256, 0, stream>>>(q, k, v, qb, kb, vb, tbl,
                                         Wq, WqT, Wk, WkT, Wv, WvT, Wout, WoT);
  // 2. projections + fused RoPE (Q,K) + fused permuted V-transpose (one launch)
  gemm_qkv_kernel<<<512, 256, 0, stream>>>(qb, WqT, Qh, kb, WkT, Kh, vb, WvT, Vt, tbl);
  // 3. differential flash attention -> AO bf16 [2048][2048]
  attn_kernel<<<512, 256, 0, stream>>>(Qh, Kh, Vt, AO, lq1, lk1, lq2, lk2, subln);
  // 4. output projection -> f32 d_out
  gemm_one_kernel<<<256, 256, 0, stream>>>(AO, WoT, out);
}

// Round 9
// 150.366 us; speedup vs baseline: 1.0576x; 1.0576x over previous
//
#include <hip/hip_runtime.h>

typedef unsigned short u16;
typedef unsigned int u32;
typedef float f32x4 __attribute__((ext_vector_type(4)));
typedef float f32x2 __attribute__((ext_vector_type(2)));
typedef unsigned int u32x2 __attribute__((ext_vector_type(2)));
typedef __bf16 bf16x8 __attribute__((ext_vector_type(8)));
typedef __bf16 bf16x4 __attribute__((ext_vector_type(4)));

#define LAMBDA_INIT_F 0.7836057665316245f
#define ONE_MINUS_LI  0.2163942334683755f
#define THR_LOG2 11.0f
// 0.125 * log2(e): fold softmax base-2 conversion into Q scaling
#define Q_SCALE 0.18033688011112042f

__device__ __forceinline__ u16 f2b(float f) {
  union { float f; u32 u; } x; x.f = f;
  u32 r = x.u + 0x7fffu + ((x.u >> 16) & 1u);
  return (u16)(r >> 16);
}

__device__ __forceinline__ f32x4 mfma16(bf16x8 a, bf16x8 b, f32x4 c) {
  return __builtin_amdgcn_mfma_f32_16x16x32_bf16(a, b, c, 0, 0, 0);
}

__device__ __forceinline__ float fexp2(float x) { return __builtin_amdgcn_exp2f(x); }

// async global->LDS, 16B per lane; LDS dest must be linear in lane order
__device__ __forceinline__ void gll16(const void* gp, void* lp) {
  __builtin_amdgcn_global_load_lds((__attribute__((address_space(1))) void*)(gp),
                                   (__attribute__((address_space(3))) void*)(lp),
                                   16, 0, 0);
}

// ------------- tiled transpose+cast body: f32 [R][C] -> bf16 [C][R] -----------
__device__ __forceinline__ void trans_body2(const float* __restrict__ in,
                                            u16* __restrict__ out, int R, int C,
                                            int bxb, int byb) {
  __shared__ float tile[32][33];
  int bx = bxb * 32;  // col base
  int by = byb * 32;  // row base
  int tx = threadIdx.x & 31, ty = threadIdx.x >> 5;
#pragma unroll
  for (int i = 0; i < 32; i += 8)
    tile[ty + i][tx] = in[(size_t)(by + ty + i) * C + bx + tx];
  __syncthreads();
#pragma unroll
  for (int i = 0; i < 32; i += 8)
    out[(size_t)(bx + ty + i) * R + by + tx] = f2b(tile[tx][ty + i]);
}

// --- fused prep: cast q/k/v -> bf16, rope cos/sin table, 4 weight transposes --
// grid 1D: [0,6144) cast, [6144,6400) table, [6400,18688) wtrans
__global__ __launch_bounds__(256) void prep_kernel(
    const float* __restrict__ q, const float* __restrict__ k, const float* __restrict__ v,
    u16* __restrict__ qb, u16* __restrict__ kb, u16* __restrict__ vb,
    f32x2* __restrict__ tbl,
    const float* __restrict__ Wq, u16* __restrict__ WqT,
    const float* __restrict__ Wk, u16* __restrict__ WkT,
    const float* __restrict__ Wv, u16* __restrict__ WvT,
    const float* __restrict__ Wo, u16* __restrict__ WoT) {
  int bid = blockIdx.x;
  if (bid < 6144) {
    int seg = bid >> 11;
    int i = (bid & 2047) * 256 + threadIdx.x;
    const float* in = seg == 0 ? q : (seg == 1 ? k : v);
    u16* out = seg == 0 ? qb : (seg == 1 ? kb : vb);
    const f32x4* p = (const f32x4*)(in + (size_t)i * 8);
    f32x4 a = p[0], b = p[1];
    union { u16 u[8]; f32x4 v; } o;
#pragma unroll
    for (int j = 0; j < 4; ++j) { o.u[j] = f2b(a[j]); o.u[4 + j] = f2b(b[j]); }
    *(f32x4*)(out + (size_t)i * 8) = o.v;
    return;
  }
  if (bid < 6400) {
    int idx = (bid - 6144) * 256 + threadIdx.x;  // t*32 + j
    int t = idx >> 5, j = idx & 31;
    float theta = (float)j * (1.0f / 32.0f);
    float denom = expf(theta * 9.210340371976184f);  // 10000^theta
    float invf = 1.0f / (denom + 1e-8f);
    float ang = (float)t * invf;
    tbl[idx] = (f32x2){cosf(ang), sinf(ang)};
    return;
  }
  int w = bid - 6400;
  if (w < 4096)      trans_body2(Wq, WqT, 2048, 2048, w & 63, w >> 6);
  else if (w < 6144) { w -= 4096; trans_body2(Wk, WkT, 2048, 1024, w & 31, w >> 5); }
  else if (w < 8192) { w -= 6144; trans_body2(Wv, WvT, 2048, 1024, w & 31, w >> 5); }
  else               { w -= 8192; trans_body2(Wo, WoT, 2048, 2048, w & 63, w >> 6); }
}

// ---------------- GEMM body: 128x128 tile, BK=64, fused epilogues -------------
// MODE 0: plain f32 C[M][N]
// MODE 1: RoPE (interleaved pairs via shfl_xor(1), table cos/sin) -> bf16
//         head-major Oh[ncol>>6][t][64]; even lanes store packed u32 pairs.
// MODE 2: V permuted transpose -> bf16 Vt[dv][2048]; within each 32-key block
//         position p = 8g + 4(i&1) + r (r-contiguous -> one 8B store per quad).
template <int MODE>
__device__ __forceinline__ void gemm_body(u16* As, u16* Bs,
                                          const u16* __restrict__ A,
                                          const u16* __restrict__ Bt,
                                          void* __restrict__ Cout,
                                          const f32x2* __restrict__ tbl,
                                          float scale,
                                          int N, int K, int bx, int by) {
  const int tid = threadIdx.x;
  const int lane = tid & 63;
  const int wave = tid >> 6;
  const int m0 = by * 128;
  const int n0 = bx * 128;
  const int wm = (wave >> 1) * 64;
  const int wn = (wave & 1) * 64;
  const int g = lane >> 4, c = lane & 15;

  f32x4 acc[4][4];
#pragma unroll
  for (int i = 0; i < 4; ++i)
#pragma unroll
    for (int j = 0; j < 4; ++j) acc[i][j] = (f32x4){0.f, 0.f, 0.f, 0.f};

  for (int k0 = 0; k0 < K; k0 += 64) {
    __syncthreads();
#pragma unroll
    for (int it = 0; it < 4; ++it) {
      int gi = it * 256 + tid;
      int R = gi >> 3;
      int lg = (gi & 7) ^ (R & 7);
      gll16(A + (size_t)(m0 + R) * K + k0 + lg * 8, As + gi * 8);
      gll16(Bt + (size_t)(n0 + R) * K + k0 + lg * 8, Bs + gi * 8);
    }
    __syncthreads();
#pragma unroll
    for (int kk = 0; kk < 2; ++kk) {
      bf16x8 af[4], bf[4];
#pragma unroll
      for (int i = 0; i < 4; ++i) {
        int ph = ((kk * 4 + g) ^ (c & 7)) * 8;
        af[i] = *(const bf16x8*)&As[(wm + i * 16 + c) * 64 + ph];
        bf[i] = *(const bf16x8*)&Bs[(wn + i * 16 + c) * 64 + ph];
      }
#pragma unroll
      for (int i = 0; i < 4; ++i)
#pragma unroll
        for (int j = 0; j < 4; ++j) acc[i][j] = mfma16(af[i], bf[j], acc[i][j]);
    }
  }

  if constexpr (MODE == 0) {
    float* C = (float*)Cout;
#pragma unroll
    for (int i = 0; i < 4; ++i)
#pragma unroll
      for (int j = 0; j < 4; ++j) {
        int mrow = m0 + wm + i * 16 + g * 4;
        int ncol = n0 + wn + j * 16 + c;
#pragma unroll
        for (int r = 0; r < 4; ++r) C[(size_t)(mrow + r) * N + ncol] = acc[i][j][r];
      }
  } else if constexpr (MODE == 1) {
    u16* Oh = (u16*)Cout;
    const bool even = (c & 1) == 0;
#pragma unroll
    for (int i = 0; i < 4; ++i)
#pragma unroll
      for (int j = 0; j < 4; ++j) {
        int mrow = m0 + wm + i * 16 + g * 4;
        int ncol = n0 + wn + j * 16 + c;
        int hh = ncol >> 6;
        int d = ncol & 63;
        int jd = d >> 1;
        f32x4 own = acc[i][j];
        f32x4 part;
#pragma unroll
        for (int r = 0; r < 4; ++r) part[r] = __shfl_xor(own[r], 1);
        if (even) {
#pragma unroll
          for (int r = 0; r < 4; ++r) {
            f32x2 cs = tbl[(mrow + r) * 32 + jd];
            float o1 = (own[r] * cs[0] - part[r] * cs[1]) * scale;
            float o2 = (own[r] * cs[1] + part[r] * cs[0]) * scale;
            u32 pk = (u32)f2b(o1) | ((u32)f2b(o2) << 16);
            *(u32*)&Oh[((size_t)hh * 2048 + mrow + r) * 64 + d] = pk;
          }
        }
      }
  } else {
    u16* Vt = (u16*)Cout;
#pragma unroll
    for (int i = 0; i < 4; ++i)
#pragma unroll
      for (int j = 0; j < 4; ++j) {
        int ncol = n0 + wn + j * 16 + c;              // dv
        int tblk = (m0 + wm + i * 16) >> 5;           // 32-key block
        int p0 = 8 * g + 4 * (i & 1);                 // permuted base, +r contiguous
        u32x2 pk;
        pk[0] = (u32)f2b(acc[i][j][0]) | ((u32)f2b(acc[i][j][1]) << 16);
        pk[1] = (u32)f2b(acc[i][j][2]) | ((u32)f2b(acc[i][j][3]) << 16);
        *(u32x2*)&Vt[(size_t)ncol * 2048 + tblk * 32 + p0] = pk;
      }
  }
}

// ------- GEMM body: 128x64 tile, BK=64 (R6-verified), plain f32 epilogue ------
__device__ __forceinline__ void gemm_body64(u16* As, u16* Bs,
                                            const u16* __restrict__ A,
                                            const u16* __restrict__ Bt,
                                            float* __restrict__ C,
                                            int N, int K, int bx, int by) {
  const int tid = threadIdx.x;
  const int lane = tid & 63;
  const int wave = tid >> 6;
  const int m0 = by * 128;
  const int n0 = bx * 64;
  const int wm = (wave >> 1) * 64;
  const int wn = (wave & 1) * 32;
  const int g = lane >> 4, c = lane & 15;

  f32x4 acc[4][2];
#pragma unroll
  for (int i = 0; i < 4; ++i)
#pragma unroll
    for (int j = 0; j < 2; ++j) acc[i][j] = (f32x4){0.f, 0.f, 0.f, 0.f};

  for (int k0 = 0; k0 < K; k0 += 64) {
    __syncthreads();
#pragma unroll
    for (int it = 0; it < 4; ++it) {
      int gi = it * 256 + tid;
      int R = gi >> 3;
      int lg = (gi & 7) ^ (R & 7);
      gll16(A + (size_t)(m0 + R) * K + k0 + lg * 8, As + gi * 8);
    }
#pragma unroll
    for (int it = 0; it < 2; ++it) {
      int gi = it * 256 + tid;
      int R = gi >> 3;
      int lg = (gi & 7) ^ (R & 7);
      gll16(Bt + (size_t)(n0 + R) * K + k0 + lg * 8, Bs + gi * 8);
    }
    __syncthreads();
#pragma unroll
    for (int kk = 0; kk < 2; ++kk) {
      bf16x8 af[4], bf[2];
      int ph = ((kk * 4 + g) ^ (c & 7)) * 8;
#pragma unroll
      for (int i = 0; i < 4; ++i) af[i] = *(const bf16x8*)&As[(wm + i * 16 + c) * 64 + ph];
#pragma unroll
      for (int j = 0; j < 2; ++j) bf[j] = *(const bf16x8*)&Bs[(wn + j * 16 + c) * 64 + ph];
#pragma unroll
      for (int i = 0; i < 4; ++i)
#pragma unroll
        for (int j = 0; j < 2; ++j) acc[i][j] = mfma16(af[i], bf[j], acc[i][j]);
    }
  }
#pragma unroll
  for (int i = 0; i < 4; ++i)
#pragma unroll
    for (int j = 0; j < 2; ++j) {
      int mrow = m0 + wm + i * 16 + g * 4;
      int ncol = n0 + wn + j * 16 + c;
#pragma unroll
      for (int r = 0; r < 4; ++r) C[(size_t)(mrow + r) * N + ncol] = acc[i][j][r];
    }
}

// fused q/k/v projections + RoPE + V-transpose epilogues: 512 blocks (2/CU)
__global__ __launch_bounds__(256, 2) void gemm_qkv_kernel(
    const u16* __restrict__ qb, const u16* __restrict__ WqT, u16* __restrict__ Qh,
    const u16* __restrict__ kb, const u16* __restrict__ WkT, u16* __restrict__ Kh,
    const u16* __restrict__ vb, const u16* __restrict__ WvT, u16* __restrict__ Vt,
    const f32x2* __restrict__ tbl) {
  __shared__ u16 As[128 * 64];
  __shared__ u16 Bs[128 * 64];
  // XCD-aware swizzle: 512 blocks, 64 consecutive work-ids per XCD
  int bid = ((blockIdx.x & 7) << 6) | (blockIdx.x >> 3);
  if (bid < 256) {
    gemm_body<1>(As, Bs, qb, WqT, Qh, tbl, Q_SCALE, 2048, 2048, bid & 15, bid >> 4);
  } else if (bid < 384) {
    int t = bid - 256;
    gemm_body<1>(As, Bs, kb, WkT, Kh, tbl, 1.0f, 1024, 2048, t & 7, t >> 3);
  } else {
    int t = bid - 384;
    gemm_body<2>(As, Bs, vb, WvT, Vt, tbl, 1.0f, 1024, 2048, t & 7, t >> 3);
  }
}

// out-projection: 128x64 tiles -> 512 blocks (2 blocks/CU, was 1/CU at 128^2)
__global__ __launch_bounds__(256, 2) void gemm_one_kernel(const u16* __restrict__ A,
                                                          const u16* __restrict__ Bt,
                                                          float* __restrict__ C) {
  __shared__ u16 As[128 * 64];
  __shared__ u16 Bs[64 * 64];
  int bid = ((blockIdx.x & 7) << 6) | (blockIdx.x >> 3);  // 512 blocks
  gemm_body64(As, Bs, A, Bt, C, 2048, 2048, bid & 31, bid >> 5);
}

// ---------------- fused differential flash attention (R6/R7 proven) -----------
// 8-wave blocks (512 thr), 256 blocks: block = 1 head x 128 q-rows; K/V staged
// once per 128 rows. Permuted Vt layout -> PV fragment = ONE ds_read_b128 at
// kb0 / kb1 (conflicts 0). Softmax exp via raw v_exp_f32.
__global__ __launch_bounds__(512, 2) void attn_kernel(const u16* __restrict__ Qb,
                                                      const u16* __restrict__ Kb,
                                                      const u16* __restrict__ Vt,
                                                      u16* __restrict__ AO,
                                                      const float* __restrict__ lq1,
                                                      const float* __restrict__ lk1,
                                                      const float* __restrict__ lq2,
                                                      const float* __restrict__ lk2,
                                                      const float* __restrict__ subln) {
  // XCD swizzle: 32 consecutive work-ids (2 heads) per XCD's L2
  const int b = ((blockIdx.x & 7) << 5) | (blockIdx.x >> 3);
  const int h = b >> 4;
  const int tid = threadIdx.x;
  const int wave = tid >> 6;
  const int lane = tid & 63;
  const int t0 = ((b & 15) * 8 + wave) * 16;
  const int g = lane >> 4, c = lane & 15;
  const int c7 = c & 7;

  __shared__ u16 smem[24576];  // 48KB: K0@0 K1@4096 V0@8192 V1@16384

  const u16* Kh = Kb + (size_t)h * 2048 * 64;
  const u16* Vh = Vt + (size_t)(h >> 1) * 128 * 2048;

  // lambda (wave-parallel)
  float myl1 = lq1[lane] * lk1[lane];
  float myl2 = lq2[lane] * lk2[lane];
#pragma unroll
  for (int off = 32; off; off >>= 1) {
    myl1 += __shfl_xor(myl1, off);
    myl2 += __shfl_xor(myl2, off);
  }
  const float lambda_full = expf(myl1) - expf(myl2) + LAMBDA_INIT_F;

  // Q fragments (B-operand: col = q-row = c, natural d-slots)
  bf16x8 qf[2][2];
#pragma unroll
  for (int e = 0; e < 2; ++e)
#pragma unroll
    for (int d = 0; d < 2; ++d)
      qf[e][d] = *(const bf16x8*)(Qb + ((size_t)(2 * h + e) * 2048 + t0 + c) * 64 + d * 32 + g * 8);

  // loop-invariant LDS read bases (u16-elem units); shared by K and V reads
  const int kb0 = c * 64 + ((g ^ c7) * 8);
  const int kb1 = kb0 ^ 32;

  // per-thread stage source bases (granule-XOR pre-swizzled)
  const u16* ksrc0;
  const u16* vsrc0;
  const u16* vsrc1;
  { int gi = tid;       int R = gi >> 3; ksrc0 = Kh + R * 64 + ((gi & 7) ^ (R & 7)) * 8; }
  { int gi = tid;       int R = gi >> 3; vsrc0 = Vh + (size_t)R * 2048 + ((gi & 7) ^ (R & 7)) * 8; }
  { int gi = 512 + tid; int R = gi >> 3; vsrc1 = Vh + (size_t)R * 2048 + ((gi & 7) ^ (R & 7)) * 8; }

  f32x4 O[2][8];
#pragma unroll
  for (int e = 0; e < 2; ++e)
#pragma unroll
    for (int f = 0; f < 8; ++f) O[e][f] = (f32x4){0.f, 0.f, 0.f, 0.f};
  float m0 = -1e30f, m1 = -1e30f, ls0 = 0.f, ls1 = 0.f;

#define STAGE(kOff, vOff, s0)                                   \
  do {                                                          \
    gll16(ksrc0 + (size_t)(s0) * 64, smem + (kOff) + tid * 8);  \
    gll16(vsrc0 + (s0), smem + (vOff) + tid * 8);               \
    gll16(vsrc1 + (s0), smem + (vOff) + 4096 + tid * 8);        \
  } while (0)

#define TILE(kOff, vOff)                                                      \
  do {                                                                        \
    bf16x8 kf[4][2];                                                          \
    _Pragma("unroll") for (int sf = 0; sf < 4; ++sf) {                        \
      kf[sf][0] = *(const bf16x8*)&smem[(kOff) + kb0 + sf * 1024];            \
      kf[sf][1] = *(const bf16x8*)&smem[(kOff) + kb1 + sf * 1024];            \
    }                                                                         \
    f32x4 sa[2][4];                                                           \
    _Pragma("unroll") for (int e = 0; e < 2; ++e)                             \
      _Pragma("unroll") for (int sf = 0; sf < 4; ++sf) {                      \
        f32x4 z = (f32x4){0.f, 0.f, 0.f, 0.f};                                \
        z = mfma16(kf[sf][0], qf[e][0], z);                                   \
        z = mfma16(kf[sf][1], qf[e][1], z);                                   \
        sa[e][sf] = z;                                                        \
      }                                                                       \
    bf16x8 vv0[8];                                                            \
    _Pragma("unroll") for (int f = 0; f < 8; ++f)                             \
      vv0[f] = *(const bf16x8*)&smem[(vOff) + kb0 + f * 1024];                \
    bf16x8 paf[2][2];                                                         \
    _Pragma("unroll") for (int e = 0; e < 2; ++e) {                           \
      float& m_e = e ? m1 : m0;                                               \
      float& ls_e = e ? ls1 : ls0;                                            \
      float mx = sa[e][0][0];                                                 \
      _Pragma("unroll") for (int sf = 0; sf < 4; ++sf)                        \
        _Pragma("unroll") for (int r = 0; r < 4; ++r)                         \
          mx = fmaxf(mx, sa[e][sf][r]);                                       \
      mx = fmaxf(mx, __shfl_xor(mx, 16));                                     \
      mx = fmaxf(mx, __shfl_xor(mx, 32));                                     \
      if (__any(mx > m_e + THR_LOG2)) {                                       \
        float mn = fmaxf(m_e, mx);                                            \
        float sc = fexp2(m_e - mn);                                           \
        m_e = mn;                                                             \
        ls_e *= sc;                                                           \
        float scr[4];                                                         \
        _Pragma("unroll") for (int r = 0; r < 4; ++r) scr[r] = __shfl(sc, g * 4 + r); \
        _Pragma("unroll") for (int ff = 0; ff < 8; ++ff)                      \
          _Pragma("unroll") for (int r = 0; r < 4; ++r) O[e][ff][r] *= scr[r]; \
      }                                                                       \
      float p[4][4];                                                          \
      float sum = 0.f;                                                        \
      _Pragma("unroll") for (int sf = 0; sf < 4; ++sf)                        \
        _Pragma("unroll") for (int r = 0; r < 4; ++r) {                       \
          float pv = fexp2(sa[e][sf][r] - m_e);                               \
          p[sf][r] = pv;                                                      \
          sum += pv;                                                          \
        }                                                                     \
      sum += __shfl_xor(sum, 16);                                             \
      sum += __shfl_xor(sum, 32);                                             \
      ls_e += sum;                                                            \
      paf[e][0] = (bf16x8){(__bf16)p[0][0], (__bf16)p[0][1], (__bf16)p[0][2], (__bf16)p[0][3], \
                           (__bf16)p[1][0], (__bf16)p[1][1], (__bf16)p[1][2], (__bf16)p[1][3]}; \
      paf[e][1] = (bf16x8){(__bf16)p[2][0], (__bf16)p[2][1], (__bf16)p[2][2], (__bf16)p[2][3], \
                           (__bf16)p[3][0], (__bf16)p[3][1], (__bf16)p[3][2], (__bf16)p[3][3]}; \
    }                                                                         \
    __builtin_amdgcn_s_setprio(1);                                            \
    bf16x8 vv1[8];                                                            \
    _Pragma("unroll") for (int f = 0; f < 8; ++f)                             \
      vv1[f] = *(const bf16x8*)&smem[(vOff) + kb1 + f * 1024];                \
    _Pragma("unroll") for (int f = 0; f < 8; ++f) {                           \
      O[0][f] = mfma16(paf[0][0], vv0[f], O[0][f]);                           \
      O[1][f] = mfma16(paf[1][0], vv0[f], O[1][f]);                           \
    }                                                                         \
    _Pragma("unroll") for (int f = 0; f < 8; ++f) {                           \
      O[0][f] = mfma16(paf[0][1], vv1[f], O[0][f]);                           \
      O[1][f] = mfma16(paf[1][1], vv1[f], O[1][f]);                           \
    }                                                                         \
    __builtin_amdgcn_s_setprio(0);                                            \
  } while (0)

  STAGE(0, 8192, 0);

#pragma unroll 1
  for (int t = 0; t < 32; t += 2) {
    __syncthreads();  // vmcnt(0): buf0 staged; all waves done with buf1
    STAGE(4096, 16384, (t + 1) * 64);
    TILE(0, 8192);
    __syncthreads();  // buf1 staged; all waves done with buf0
    if (t < 30) STAGE(0, 8192, (t + 2) * 64);
    TILE(4096, 16384);
  }

  // epilogue: redistribute 1/ls from c-layout to (g,r)-layout
  float inv0 = 1.f / ls0, inv1 = 1.f / ls1;
  float i0[4], i1[4];
#pragma unroll
  for (int r = 0; r < 4; ++r) {
    i0[r] = __shfl(inv0, g * 4 + r);
    i1[r] = __shfl(inv1, g * 4 + r);
  }
  float res[8][4];
  float ss[4] = {0.f, 0.f, 0.f, 0.f};
#pragma unroll
  for (int f = 0; f < 8; ++f)
#pragma unroll
    for (int r = 0; r < 4; ++r) {
      float vv = O[0][f][r] * i0[r] - lambda_full * (O[1][f][r] * i1[r]);
      res[f][r] = vv;
      ss[r] += vv * vv;
    }
#pragma unroll
  for (int off = 1; off < 16; off <<= 1)
#pragma unroll
    for (int r = 0; r < 4; ++r) ss[r] += __shfl_xor(ss[r], off);
  float rms[4];
#pragma unroll
  for (int r = 0; r < 4; ++r)
    rms[r] = rsqrtf(ss[r] * (1.0f / 128.0f) + 1e-5f) * ONE_MINUS_LI;
  float w[8];
#pragma unroll
  for (int f = 0; f < 8; ++f) w[f] = subln[f * 16 + c];
#pragma unroll
  for (int f = 0; f < 8; ++f)
#pragma unroll
    for (int r = 0; r < 4; ++r)
      AO[(size_t)(t0 + g * 4 + r) * 2048 + h * 128 + f * 16 + c] = f2b(res[f][r] * rms[r] * w[f]);
}

// ------------------------------------------------------------------------------
extern "C" void kernel_launch(void* const* d_in, const int* in_sizes, int n_in,
                              void* d_out, int out_size, void* d_ws, size_t ws_size,
                              hipStream_t stream) {
  const float* q     = (const float*)d_in[0];
  const float* k     = (const float*)d_in[1];
  const float* v     = (const float*)d_in[2];
  const float* Wq    = (const float*)d_in[3];
  const float* Wk    = (const float*)d_in[4];
  const float* Wv    = (const float*)d_in[5];
  const float* Wout  = (const float*)d_in[6];
  const float* lq1   = (const float*)d_in[7];
  const float* lk1   = (const float*)d_in[8];
  const float* lq2   = (const float*)d_in[9];
  const float* lk2   = (const float*)d_in[10];
  const float* subln = (const float*)d_in[11];
  float* out = (float*)d_out;

  char* ws = (char*)d_ws;
  size_t off = 0;
  auto alloc = [&](size_t bytes) -> void* {
    void* p = ws + off;
    off += (bytes + 255) & ~(size_t)255;
    return p;
  };
  u16* qb  = (u16*)alloc(2048ull * 2048 * 2);
  u16* kb  = (u16*)alloc(2048ull * 2048 * 2);
  u16* vb  = (u16*)alloc(2048ull * 2048 * 2);
  u16* WqT = (u16*)alloc(2048ull * 2048 * 2);
  u16* WkT = (u16*)alloc(1024ull * 2048 * 2);
  u16* WvT = (u16*)alloc(1024ull * 2048 * 2);
  u16* WoT = (u16*)alloc(2048ull * 2048 * 2);
  f32x2* tbl = (f32x2*)alloc(2048ull * 32 * 8);
  u16* Qh  = (u16*)alloc(32ull * 2048 * 64 * 2);
  u16* Kh  = (u16*)alloc(16ull * 2048 * 64 * 2);
  u16* Vt  = (u16*)alloc(1024ull * 2048 * 2);
  u16* AO  = (u16*)alloc(2048ull * 2048 * 2);

  // 1. fused prep: cast q/k/v + rope table + all weight transposes (one launch)
  prep_kernel<<<18688, 256, 0, stream>>>(q, k, v, qb, kb, vb, tbl,
                                         Wq, WqT, Wk, WkT, Wv, WvT, Wout, WoT);
  // 2. projections + fused RoPE (Q,K) + fused permuted V-transpose (one launch)
  gemm_qkv_kernel<<<512, 256, 0, stream>>>(qb, WqT, Qh, kb, WkT, Kh, vb, WvT, Vt, tbl);
  // 3. differential flash attention -> AO bf16 [2048][2048]
  attn_kernel<<<256, 512, 0, stream>>>(Qh, Kh, Vt, AO, lq1, lk1, lq2, lk2, subln);
  // 4. output projection -> f32 d_out (128x64 tiles, 2 blocks/CU)
  gemm_one_kernel<<<512, 256, 0, stream>>>(AO, WoT, out);
}

// Round 10
// 149.979 us; speedup vs baseline: 1.0603x; 1.0026x over previous
//
#include <hip/hip_runtime.h>

typedef unsigned short u16;
typedef unsigned int u32;
typedef float f32x4 __attribute__((ext_vector_type(4)));
typedef float f32x2 __attribute__((ext_vector_type(2)));
typedef unsigned int u32x2 __attribute__((ext_vector_type(2)));
typedef __bf16 bf16x8 __attribute__((ext_vector_type(8)));
typedef __bf16 bf16x4 __attribute__((ext_vector_type(4)));

#define LAMBDA_INIT_F 0.7836057665316245f
#define ONE_MINUS_LI  0.2163942334683755f
#define THR_LOG2 11.0f
// 0.125 * log2(e): fold softmax base-2 conversion into Q scaling
#define Q_SCALE 0.18033688011112042f

__device__ __forceinline__ u16 f2b(float f) {
  union { float f; u32 u; } x; x.f = f;
  u32 r = x.u + 0x7fffu + ((x.u >> 16) & 1u);
  return (u16)(r >> 16);
}

__device__ __forceinline__ f32x4 mfma16(bf16x8 a, bf16x8 b, f32x4 c) {
  return __builtin_amdgcn_mfma_f32_16x16x32_bf16(a, b, c, 0, 0, 0);
}

__device__ __forceinline__ float fexp2(float x) { return __builtin_amdgcn_exp2f(x); }

// async global->LDS, 16B per lane; LDS dest must be linear in lane order
__device__ __forceinline__ void gll16(const void* gp, void* lp) {
  __builtin_amdgcn_global_load_lds((__attribute__((address_space(1))) void*)(gp),
                                   (__attribute__((address_space(3))) void*)(lp),
                                   16, 0, 0);
}

// ------------- tiled transpose+cast body: f32 [R][C] -> bf16 [C][R] -----------
__device__ __forceinline__ void trans_body2(const float* __restrict__ in,
                                            u16* __restrict__ out, int R, int C,
                                            int bxb, int byb) {
  __shared__ float tile[32][33];
  int bx = bxb * 32;  // col base
  int by = byb * 32;  // row base
  int tx = threadIdx.x & 31, ty = threadIdx.x >> 5;
#pragma unroll
  for (int i = 0; i < 32; i += 8)
    tile[ty + i][tx] = in[(size_t)(by + ty + i) * C + bx + tx];
  __syncthreads();
#pragma unroll
  for (int i = 0; i < 32; i += 8)
    out[(size_t)(bx + ty + i) * R + by + tx] = f2b(tile[tx][ty + i]);
}

// --- fused prep: cast q/k/v -> bf16, rope cos/sin table, 4 weight transposes --
// grid 1D: [0,6144) cast, [6144,6400) table, [6400,18688) wtrans
__global__ __launch_bounds__(256) void prep_kernel(
    const float* __restrict__ q, const float* __restrict__ k, const float* __restrict__ v,
    u16* __restrict__ qb, u16* __restrict__ kb, u16* __restrict__ vb,
    f32x2* __restrict__ tbl,
    const float* __restrict__ Wq, u16* __restrict__ WqT,
    const float* __restrict__ Wk, u16* __restrict__ WkT,
    const float* __restrict__ Wv, u16* __restrict__ WvT,
    const float* __restrict__ Wo, u16* __restrict__ WoT) {
  int bid = blockIdx.x;
  if (bid < 6144) {
    int seg = bid >> 11;
    int i = (bid & 2047) * 256 + threadIdx.x;
    const float* in = seg == 0 ? q : (seg == 1 ? k : v);
    u16* out = seg == 0 ? qb : (seg == 1 ? kb : vb);
    const f32x4* p = (const f32x4*)(in + (size_t)i * 8);
    f32x4 a = p[0], b = p[1];
    union { u16 u[8]; f32x4 v; } o;
#pragma unroll
    for (int j = 0; j < 4; ++j) { o.u[j] = f2b(a[j]); o.u[4 + j] = f2b(b[j]); }
    *(f32x4*)(out + (size_t)i * 8) = o.v;
    return;
  }
  if (bid < 6400) {
    int idx = (bid - 6144) * 256 + threadIdx.x;  // t*32 + j
    int t = idx >> 5, j = idx & 31;
    float theta = (float)j * (1.0f / 32.0f);
    float denom = expf(theta * 9.210340371976184f);  // 10000^theta
    float invf = 1.0f / (denom + 1e-8f);
    float ang = (float)t * invf;
    tbl[idx] = (f32x2){cosf(ang), sinf(ang)};
    return;
  }
  int w = bid - 6400;
  if (w < 4096)      trans_body2(Wq, WqT, 2048, 2048, w & 63, w >> 6);
  else if (w < 6144) { w -= 4096; trans_body2(Wk, WkT, 2048, 1024, w & 31, w >> 5); }
  else if (w < 8192) { w -= 6144; trans_body2(Wv, WvT, 2048, 1024, w & 31, w >> 5); }
  else               { w -= 8192; trans_body2(Wo, WoT, 2048, 2048, w & 63, w >> 6); }
}

// ---------------- GEMM body: 128x128 tile, BK=64, fused epilogues -------------
// MODE 0: plain f32 C[M][N]
// MODE 1: RoPE (interleaved pairs via shfl_xor(1), table cos/sin) -> bf16
//         head-major Oh[ncol>>6][t][64]; even lanes store packed u32 pairs.
// MODE 2: V permuted transpose -> bf16 Vt[dv][2048]; within each 32-key block
//         position p = 8g + 4(i&1) + r (r-contiguous -> one 8B store per quad).
template <int MODE>
__device__ __forceinline__ void gemm_body(u16* As, u16* Bs,
                                          const u16* __restrict__ A,
                                          const u16* __restrict__ Bt,
                                          void* __restrict__ Cout,
                                          const f32x2* __restrict__ tbl,
                                          float scale,
                                          int N, int K, int bx, int by) {
  const int tid = threadIdx.x;
  const int lane = tid & 63;
  const int wave = tid >> 6;
  const int m0 = by * 128;
  const int n0 = bx * 128;
  const int wm = (wave >> 1) * 64;
  const int wn = (wave & 1) * 64;
  const int g = lane >> 4, c = lane & 15;

  f32x4 acc[4][4];
#pragma unroll
  for (int i = 0; i < 4; ++i)
#pragma unroll
    for (int j = 0; j < 4; ++j) acc[i][j] = (f32x4){0.f, 0.f, 0.f, 0.f};

  for (int k0 = 0; k0 < K; k0 += 64) {
    __syncthreads();
#pragma unroll
    for (int it = 0; it < 4; ++it) {
      int gi = it * 256 + tid;
      int R = gi >> 3;
      int lg = (gi & 7) ^ (R & 7);
      gll16(A + (size_t)(m0 + R) * K + k0 + lg * 8, As + gi * 8);
      gll16(Bt + (size_t)(n0 + R) * K + k0 + lg * 8, Bs + gi * 8);
    }
    __syncthreads();
#pragma unroll
    for (int kk = 0; kk < 2; ++kk) {
      bf16x8 af[4], bf[4];
#pragma unroll
      for (int i = 0; i < 4; ++i) {
        int ph = ((kk * 4 + g) ^ (c & 7)) * 8;
        af[i] = *(const bf16x8*)&As[(wm + i * 16 + c) * 64 + ph];
        bf[i] = *(const bf16x8*)&Bs[(wn + i * 16 + c) * 64 + ph];
      }
#pragma unroll
      for (int i = 0; i < 4; ++i)
#pragma unroll
        for (int j = 0; j < 4; ++j) acc[i][j] = mfma16(af[i], bf[j], acc[i][j]);
    }
  }

  if constexpr (MODE == 0) {
    float* C = (float*)Cout;
#pragma unroll
    for (int i = 0; i < 4; ++i)
#pragma unroll
      for (int j = 0; j < 4; ++j) {
        int mrow = m0 + wm + i * 16 + g * 4;
        int ncol = n0 + wn + j * 16 + c;
#pragma unroll
        for (int r = 0; r < 4; ++r) C[(size_t)(mrow + r) * N + ncol] = acc[i][j][r];
      }
  } else if constexpr (MODE == 1) {
    u16* Oh = (u16*)Cout;
    const bool even = (c & 1) == 0;
#pragma unroll
    for (int i = 0; i < 4; ++i)
#pragma unroll
      for (int j = 0; j < 4; ++j) {
        int mrow = m0 + wm + i * 16 + g * 4;
        int ncol = n0 + wn + j * 16 + c;
        int hh = ncol >> 6;
        int d = ncol & 63;
        int jd = d >> 1;
        f32x4 own = acc[i][j];
        f32x4 part;
#pragma unroll
        for (int r = 0; r < 4; ++r) part[r] = __shfl_xor(own[r], 1);
        if (even) {
#pragma unroll
          for (int r = 0; r < 4; ++r) {
            f32x2 cs = tbl[(mrow + r) * 32 + jd];
            float o1 = (own[r] * cs[0] - part[r] * cs[1]) * scale;
            float o2 = (own[r] * cs[1] + part[r] * cs[0]) * scale;
            u32 pk = (u32)f2b(o1) | ((u32)f2b(o2) << 16);
            *(u32*)&Oh[((size_t)hh * 2048 + mrow + r) * 64 + d] = pk;
          }
        }
      }
  } else {
    u16* Vt = (u16*)Cout;
#pragma unroll
    for (int i = 0; i < 4; ++i)
#pragma unroll
      for (int j = 0; j < 4; ++j) {
        int ncol = n0 + wn + j * 16 + c;              // dv
        int tblk = (m0 + wm + i * 16) >> 5;           // 32-key block
        int p0 = 8 * g + 4 * (i & 1);                 // permuted base, +r contiguous
        u32x2 pk;
        pk[0] = (u32)f2b(acc[i][j][0]) | ((u32)f2b(acc[i][j][1]) << 16);
        pk[1] = (u32)f2b(acc[i][j][2]) | ((u32)f2b(acc[i][j][3]) << 16);
        *(u32x2*)&Vt[(size_t)ncol * 2048 + tblk * 32 + p0] = pk;
      }
  }
}

// ------- GEMM body: 128x64 tile, BK=64 (R6-verified), plain f32 epilogue ------
__device__ __forceinline__ void gemm_body64(u16* As, u16* Bs,
                                            const u16* __restrict__ A,
                                            const u16* __restrict__ Bt,
                                            float* __restrict__ C,
                                            int N, int K, int bx, int by) {
  const int tid = threadIdx.x;
  const int lane = tid & 63;
  const int wave = tid >> 6;
  const int m0 = by * 128;
  const int n0 = bx * 64;
  const int wm = (wave >> 1) * 64;
  const int wn = (wave & 1) * 32;
  const int g = lane >> 4, c = lane & 15;

  f32x4 acc[4][2];
#pragma unroll
  for (int i = 0; i < 4; ++i)
#pragma unroll
    for (int j = 0; j < 2; ++j) acc[i][j] = (f32x4){0.f, 0.f, 0.f, 0.f};

  for (int k0 = 0; k0 < K; k0 += 64) {
    __syncthreads();
#pragma unroll
    for (int it = 0; it < 4; ++it) {
      int gi = it * 256 + tid;
      int R = gi >> 3;
      int lg = (gi & 7) ^ (R & 7);
      gll16(A + (size_t)(m0 + R) * K + k0 + lg * 8, As + gi * 8);
    }
#pragma unroll
    for (int it = 0; it < 2; ++it) {
      int gi = it * 256 + tid;
      int R = gi >> 3;
      int lg = (gi & 7) ^ (R & 7);
      gll16(Bt + (size_t)(n0 + R) * K + k0 + lg * 8, Bs + gi * 8);
    }
    __syncthreads();
#pragma unroll
    for (int kk = 0; kk < 2; ++kk) {
      bf16x8 af[4], bf[2];
      int ph = ((kk * 4 + g) ^ (c & 7)) * 8;
#pragma unroll
      for (int i = 0; i < 4; ++i) af[i] = *(const bf16x8*)&As[(wm + i * 16 + c) * 64 + ph];
#pragma unroll
      for (int j = 0; j < 2; ++j) bf[j] = *(const bf16x8*)&Bs[(wn + j * 16 + c) * 64 + ph];
#pragma unroll
      for (int i = 0; i < 4; ++i)
#pragma unroll
        for (int j = 0; j < 2; ++j) acc[i][j] = mfma16(af[i], bf[j], acc[i][j]);
    }
  }
#pragma unroll
  for (int i = 0; i < 4; ++i)
#pragma unroll
    for (int j = 0; j < 2; ++j) {
      int mrow = m0 + wm + i * 16 + g * 4;
      int ncol = n0 + wn + j * 16 + c;
#pragma unroll
      for (int r = 0; r < 4; ++r) C[(size_t)(mrow + r) * N + ncol] = acc[i][j][r];
    }
}

// fused q/k/v projections + RoPE + V-transpose epilogues: 512 blocks (2/CU)
__global__ __launch_bounds__(256, 2) void gemm_qkv_kernel(
    const u16* __restrict__ qb, const u16* __restrict__ WqT, u16* __restrict__ Qh,
    const u16* __restrict__ kb, const u16* __restrict__ WkT, u16* __restrict__ Kh,
    const u16* __restrict__ vb, const u16* __restrict__ WvT, u16* __restrict__ Vt,
    const f32x2* __restrict__ tbl) {
  __shared__ u16 As[128 * 64];
  __shared__ u16 Bs[128 * 64];
  // XCD-aware swizzle: 512 blocks, 64 consecutive work-ids per XCD
  int bid = ((blockIdx.x & 7) << 6) | (blockIdx.x >> 3);
  if (bid < 256) {
    gemm_body<1>(As, Bs, qb, WqT, Qh, tbl, Q_SCALE, 2048, 2048, bid & 15, bid >> 4);
  } else if (bid < 384) {
    int t = bid - 256;
    gemm_body<1>(As, Bs, kb, WkT, Kh, tbl, 1.0f, 1024, 2048, t & 7, t >> 3);
  } else {
    int t = bid - 384;
    gemm_body<2>(As, Bs, vb, WvT, Vt, tbl, 1.0f, 1024, 2048, t & 7, t >> 3);
  }
}

// out-projection: 128x64 tiles -> 512 blocks (2 blocks/CU)
__global__ __launch_bounds__(256, 2) void gemm_one_kernel(const u16* __restrict__ A,
                                                          const u16* __restrict__ Bt,
                                                          float* __restrict__ C) {
  __shared__ u16 As[128 * 64];
  __shared__ u16 Bs[64 * 64];
  int bid = ((blockIdx.x & 7) << 6) | (blockIdx.x >> 3);  // 512 blocks
  gemm_body64(As, Bs, A, Bt, C, 2048, 2048, bid & 31, bid >> 5);
}

// ---------------- fused differential flash attention --------------------------
// R9 math (proven) with 2-tile mega-phases: 4 LDS tile-slots (96KB), stage 128
// keys per barrier-pair -> half the barriers, 2 unrolled TILEs of straight-line
// code between barriers for intra-wave QK/softmax/PV overlap.
// K slots: 0,4096,8192,12288 elems; V slots: 16384,24576,32768,40960 elems.
__global__ __launch_bounds__(512, 2) void attn_kernel(const u16* __restrict__ Qb,
                                                      const u16* __restrict__ Kb,
                                                      const u16* __restrict__ Vt,
                                                      u16* __restrict__ AO,
                                                      const float* __restrict__ lq1,
                                                      const float* __restrict__ lk1,
                                                      const float* __restrict__ lq2,
                                                      const float* __restrict__ lk2,
                                                      const float* __restrict__ subln) {
  // XCD swizzle: 32 consecutive work-ids (2 heads) per XCD's L2
  const int b = ((blockIdx.x & 7) << 5) | (blockIdx.x >> 3);
  const int h = b >> 4;
  const int tid = threadIdx.x;
  const int wave = tid >> 6;
  const int lane = tid & 63;
  const int t0 = ((b & 15) * 8 + wave) * 16;
  const int g = lane >> 4, c = lane & 15;
  const int c7 = c & 7;

  __shared__ u16 smem[49152];  // 96KB: K slots 0/4096/8192/12288, V 16384/24576/32768/40960

  const u16* Kh = Kb + (size_t)h * 2048 * 64;
  const u16* Vh = Vt + (size_t)(h >> 1) * 128 * 2048;

  // lambda (wave-parallel)
  float myl1 = lq1[lane] * lk1[lane];
  float myl2 = lq2[lane] * lk2[lane];
#pragma unroll
  for (int off = 32; off; off >>= 1) {
    myl1 += __shfl_xor(myl1, off);
    myl2 += __shfl_xor(myl2, off);
  }
  const float lambda_full = expf(myl1) - expf(myl2) + LAMBDA_INIT_F;

  // Q fragments (B-operand: col = q-row = c, natural d-slots)
  bf16x8 qf[2][2];
#pragma unroll
  for (int e = 0; e < 2; ++e)
#pragma unroll
    for (int d = 0; d < 2; ++d)
      qf[e][d] = *(const bf16x8*)(Qb + ((size_t)(2 * h + e) * 2048 + t0 + c) * 64 + d * 32 + g * 8);

  // loop-invariant LDS read bases (u16-elem units); shared by K and V reads
  const int kb0 = c * 64 + ((g ^ c7) * 8);
  const int kb1 = kb0 ^ 32;

  // per-thread stage source bases (granule-XOR pre-swizzled)
  const u16* ksrc0;
  const u16* vsrc0;
  const u16* vsrc1;
  { int gi = tid;       int R = gi >> 3; ksrc0 = Kh + R * 64 + ((gi & 7) ^ (R & 7)) * 8; }
  { int gi = tid;       int R = gi >> 3; vsrc0 = Vh + (size_t)R * 2048 + ((gi & 7) ^ (R & 7)) * 8; }
  { int gi = 512 + tid; int R = gi >> 3; vsrc1 = Vh + (size_t)R * 2048 + ((gi & 7) ^ (R & 7)) * 8; }

  f32x4 O[2][8];
#pragma unroll
  for (int e = 0; e < 2; ++e)
#pragma unroll
    for (int f = 0; f < 8; ++f) O[e][f] = (f32x4){0.f, 0.f, 0.f, 0.f};
  float m0 = -1e30f, m1 = -1e30f, ls0 = 0.f, ls1 = 0.f;

// stage 128 keys (2 tiles) into slot pair (kOffA/kOffB, vOffA/vOffB)
#define STAGE2(kOffA, kOffB, vOffA, vOffB, s0)                          \
  do {                                                                  \
    gll16(ksrc0 + (size_t)(s0) * 64, smem + (kOffA) + tid * 8);         \
    gll16(ksrc0 + (size_t)((s0) + 64) * 64, smem + (kOffB) + tid * 8);  \
    gll16(vsrc0 + (s0), smem + (vOffA) + tid * 8);                      \
    gll16(vsrc1 + (s0), smem + (vOffA) + 4096 + tid * 8);               \
    gll16(vsrc0 + (s0) + 64, smem + (vOffB) + tid * 8);                 \
    gll16(vsrc1 + (s0) + 64, smem + (vOffB) + 4096 + tid * 8);          \
  } while (0)

#define TILE(kOff, vOff)                                                      \
  do {                                                                        \
    bf16x8 kf[4][2];                                                          \
    _Pragma("unroll") for (int sf = 0; sf < 4; ++sf) {                        \
      kf[sf][0] = *(const bf16x8*)&smem[(kOff) + kb0 + sf * 1024];            \
      kf[sf][1] = *(const bf16x8*)&smem[(kOff) + kb1 + sf * 1024];            \
    }                                                                         \
    f32x4 sa[2][4];                                                           \
    _Pragma("unroll") for (int e = 0; e < 2; ++e)                             \
      _Pragma("unroll") for (int sf = 0; sf < 4; ++sf) {                      \
        f32x4 z = (f32x4){0.f, 0.f, 0.f, 0.f};                                \
        z = mfma16(kf[sf][0], qf[e][0], z);                                   \
        z = mfma16(kf[sf][1], qf[e][1], z);                                   \
        sa[e][sf] = z;                                                        \
      }                                                                       \
    bf16x8 vv0[8];                                                            \
    _Pragma("unroll") for (int f = 0; f < 8; ++f)                             \
      vv0[f] = *(const bf16x8*)&smem[(vOff) + kb0 + f * 1024];                \
    bf16x8 paf[2][2];                                                         \
    _Pragma("unroll") for (int e = 0; e < 2; ++e) {                           \
      float& m_e = e ? m1 : m0;                                               \
      float& ls_e = e ? ls1 : ls0;                                            \
      float mx = sa[e][0][0];                                                 \
      _Pragma("unroll") for (int sf = 0; sf < 4; ++sf)                        \
        _Pragma("unroll") for (int r = 0; r < 4; ++r)                         \
          mx = fmaxf(mx, sa[e][sf][r]);                                       \
      mx = fmaxf(mx, __shfl_xor(mx, 16));                                     \
      mx = fmaxf(mx, __shfl_xor(mx, 32));                                     \
      if (__any(mx > m_e + THR_LOG2)) {                                       \
        float mn = fmaxf(m_e, mx);                                            \
        float sc = fexp2(m_e - mn);                                           \
        m_e = mn;                                                             \
        ls_e *= sc;                                                           \
        float scr[4];                                                         \
        _Pragma("unroll") for (int r = 0; r < 4; ++r) scr[r] = __shfl(sc, g * 4 + r); \
        _Pragma("unroll") for (int ff = 0; ff < 8; ++ff)                      \
          _Pragma("unroll") for (int r = 0; r < 4; ++r) O[e][ff][r] *= scr[r]; \
      }                                                                       \
      float p[4][4];                                                          \
      float sum = 0.f;                                                        \
      _Pragma("unroll") for (int sf = 0; sf < 4; ++sf)                        \
        _Pragma("unroll") for (int r = 0; r < 4; ++r) {                       \
          float pv = fexp2(sa[e][sf][r] - m_e);                               \
          p[sf][r] = pv;                                                      \
          sum += pv;                                                          \
        }                                                                     \
      sum += __shfl_xor(sum, 16);                                             \
      sum += __shfl_xor(sum, 32);                                             \
      ls_e += sum;                                                            \
      paf[e][0] = (bf16x8){(__bf16)p[0][0], (__bf16)p[0][1], (__bf16)p[0][2], (__bf16)p[0][3], \
                           (__bf16)p[1][0], (__bf16)p[1][1], (__bf16)p[1][2], (__bf16)p[1][3]}; \
      paf[e][1] = (bf16x8){(__bf16)p[2][0], (__bf16)p[2][1], (__bf16)p[2][2], (__bf16)p[2][3], \
                           (__bf16)p[3][0], (__bf16)p[3][1], (__bf16)p[3][2], (__bf16)p[3][3]}; \
    }                                                                         \
    __builtin_amdgcn_s_setprio(1);                                            \
    bf16x8 vv1[8];                                                            \
    _Pragma("unroll") for (int f = 0; f < 8; ++f)                             \
      vv1[f] = *(const bf16x8*)&smem[(vOff) + kb1 + f * 1024];                \
    _Pragma("unroll") for (int f = 0; f < 8; ++f) {                           \
      O[0][f] = mfma16(paf[0][0], vv0[f], O[0][f]);                           \
      O[1][f] = mfma16(paf[1][0], vv0[f], O[1][f]);                           \
    }                                                                         \
    _Pragma("unroll") for (int f = 0; f < 8; ++f) {                           \
      O[0][f] = mfma16(paf[0][1], vv1[f], O[0][f]);                           \
      O[1][f] = mfma16(paf[1][1], vv1[f], O[1][f]);                           \
    }                                                                         \
    __builtin_amdgcn_s_setprio(0);                                            \
  } while (0)

  STAGE2(0, 4096, 16384, 24576, 0);

#pragma unroll 1
  for (int t = 0; t < 16; t += 2) {
    __syncthreads();  // pair A (slots 0,1) staged; all waves done with pair B
    STAGE2(8192, 12288, 32768, 40960, (t + 1) * 128);
    TILE(0, 16384);
    TILE(4096, 24576);
    __syncthreads();  // pair B (slots 2,3) staged; all waves done with pair A
    if (t < 14) STAGE2(0, 4096, 16384, 24576, (t + 2) * 128);
    TILE(8192, 32768);
    TILE(12288, 40960);
  }

  // epilogue: redistribute 1/ls from c-layout to (g,r)-layout
  float inv0 = 1.f / ls0, inv1 = 1.f / ls1;
  float i0[4], i1[4];
#pragma unroll
  for (int r = 0; r < 4; ++r) {
    i0[r] = __shfl(inv0, g * 4 + r);
    i1[r] = __shfl(inv1, g * 4 + r);
  }
  float res[8][4];
  float ss[4] = {0.f, 0.f, 0.f, 0.f};
#pragma unroll
  for (int f = 0; f < 8; ++f)
#pragma unroll
    for (int r = 0; r < 4; ++r) {
      float vv = O[0][f][r] * i0[r] - lambda_full * (O[1][f][r] * i1[r]);
      res[f][r] = vv;
      ss[r] += vv * vv;
    }
#pragma unroll
  for (int off = 1; off < 16; off <<= 1)
#pragma unroll
    for (int r = 0; r < 4; ++r) ss[r] += __shfl_xor(ss[r], off);
  float rms[4];
#pragma unroll
  for (int r = 0; r < 4; ++r)
    rms[r] = rsqrtf(ss[r] * (1.0f / 128.0f) + 1e-5f) * ONE_MINUS_LI;
  float w[8];
#pragma unroll
  for (int f = 0; f < 8; ++f) w[f] = subln[f * 16 + c];
#pragma unroll
  for (int f = 0; f < 8; ++f)
#pragma unroll
    for (int r = 0; r < 4; ++r)
      AO[(size_t)(t0 + g * 4 + r) * 2048 + h * 128 + f * 16 + c] = f2b(res[f][r] * rms[r] * w[f]);
}

// ------------------------------------------------------------------------------
extern "C" void kernel_launch(void* const* d_in, const int* in_sizes, int n_in,
                              void* d_out, int out_size, void* d_ws, size_t ws_size,
                              hipStream_t stream) {
  const float* q     = (const float*)d_in[0];
  const float* k     = (const float*)d_in[1];
  const float* v     = (const float*)d_in[2];
  const float* Wq    = (const float*)d_in[3];
  const float* Wk    = (const float*)d_in[4];
  const float* Wv    = (const float*)d_in[5];
  const float* Wout  = (const float*)d_in[6];
  const float* lq1   = (const float*)d_in[7];
  const float* lk1   = (const float*)d_in[8];
  const float* lq2   = (const float*)d_in[9];
  const float* lk2   = (const float*)d_in[10];
  const float* subln = (const float*)d_in[11];
  float* out = (float*)d_out;

  char* ws = (char*)d_ws;
  size_t off = 0;
  auto alloc = [&](size_t bytes) -> void* {
    void* p = ws + off;
    off += (bytes + 255) & ~(size_t)255;
    return p;
  };
  u16* qb  = (u16*)alloc(2048ull * 2048 * 2);
  u16* kb  = (u16*)alloc(2048ull * 2048 * 2);
  u16* vb  = (u16*)alloc(2048ull * 2048 * 2);
  u16* WqT = (u16*)alloc(2048ull * 2048 * 2);
  u16* WkT = (u16*)alloc(1024ull * 2048 * 2);
  u16* WvT = (u16*)alloc(1024ull * 2048 * 2);
  u16* WoT = (u16*)alloc(2048ull * 2048 * 2);
  f32x2* tbl = (f32x2*)alloc(2048ull * 32 * 8);
  u16* Qh  = (u16*)alloc(32ull * 2048 * 64 * 2);
  u16* Kh  = (u16*)alloc(16ull * 2048 * 64 * 2);
  u16* Vt  = (u16*)alloc(1024ull * 2048 * 2);
  u16* AO  = (u16*)alloc(2048ull * 2048 * 2);

  // 1. fused prep: cast q/k/v + rope table + all weight transposes (one launch)
  prep_kernel<<<18688, 256, 0, stream>>>(q, k, v, qb, kb, vb, tbl,
                                         Wq, WqT, Wk, WkT, Wv, WvT, Wout, WoT);
  // 2. projections + fused RoPE (Q,K) + fused permuted V-transpose (one launch)
  gemm_qkv_kernel<<<512, 256, 0, stream>>>(qb, WqT, Qh, kb, WkT, Kh, vb, WvT, Vt, tbl);
  // 3. differential flash attention -> AO bf16 [2048][2048]
  attn_kernel<<<256, 512, 0, stream>>>(Qh, Kh, Vt, AO, lq1, lk1, lq2, lk2, subln);
  // 4. output projection -> f32 d_out (128x64 tiles, 2 blocks/CU)
  gemm_one_kernel<<<512, 256, 0, stream>>>(AO, WoT, out);
}

// Round 11
// 142.783 us; speedup vs baseline: 1.1138x; 1.0504x over previous
//
#include <hip/hip_runtime.h>

typedef unsigned short u16;
typedef unsigned int u32;
typedef float f32x4 __attribute__((ext_vector_type(4)));
typedef float f32x2 __attribute__((ext_vector_type(2)));
typedef unsigned int u32x2 __attribute__((ext_vector_type(2)));
typedef __bf16 bf16x8 __attribute__((ext_vector_type(8)));
typedef __bf16 bf16x4 __attribute__((ext_vector_type(4)));

#define LAMBDA_INIT_F 0.7836057665316245f
#define ONE_MINUS_LI  0.2163942334683755f
#define THR_LOG2 11.0f
// 0.125 * log2(e): fold softmax base-2 conversion into Q scaling
#define Q_SCALE 0.18033688011112042f

__device__ __forceinline__ u16 f2b(float f) {
  union { float f; u32 u; } x; x.f = f;
  u32 r = x.u + 0x7fffu + ((x.u >> 16) & 1u);
  return (u16)(r >> 16);
}

__device__ __forceinline__ f32x4 mfma16(bf16x8 a, bf16x8 b, f32x4 c) {
  return __builtin_amdgcn_mfma_f32_16x16x32_bf16(a, b, c, 0, 0, 0);
}

__device__ __forceinline__ float fexp2(float x) { return __builtin_amdgcn_exp2f(x); }

// async global->LDS, 16B per lane; LDS dest must be linear in lane order
__device__ __forceinline__ void gll16(const void* gp, void* lp) {
  __builtin_amdgcn_global_load_lds((__attribute__((address_space(1))) void*)(gp),
                                   (__attribute__((address_space(3))) void*)(lp),
                                   16, 0, 0);
}

// ------------- tiled transpose+cast body: f32 [R][C] -> bf16 [C][R] -----------
__device__ __forceinline__ void trans_body2(const float* __restrict__ in,
                                            u16* __restrict__ out, int R, int C,
                                            int bxb, int byb) {
  __shared__ float tile[32][33];
  int bx = bxb * 32;  // col base
  int by = byb * 32;  // row base
  int tx = threadIdx.x & 31, ty = threadIdx.x >> 5;
#pragma unroll
  for (int i = 0; i < 32; i += 8)
    tile[ty + i][tx] = in[(size_t)(by + ty + i) * C + bx + tx];
  __syncthreads();
#pragma unroll
  for (int i = 0; i < 32; i += 8)
    out[(size_t)(bx + ty + i) * R + by + tx] = f2b(tile[tx][ty + i]);
}

// --- fused prep: cast q/k/v -> bf16, rope cos/sin table, 4 weight transposes --
// grid 1D: [0,6144) cast, [6144,6400) table, [6400,18688) wtrans
__global__ __launch_bounds__(256) void prep_kernel(
    const float* __restrict__ q, const float* __restrict__ k, const float* __restrict__ v,
    u16* __restrict__ qb, u16* __restrict__ kb, u16* __restrict__ vb,
    f32x2* __restrict__ tbl,
    const float* __restrict__ Wq, u16* __restrict__ WqT,
    const float* __restrict__ Wk, u16* __restrict__ WkT,
    const float* __restrict__ Wv, u16* __restrict__ WvT,
    const float* __restrict__ Wo, u16* __restrict__ WoT) {
  int bid = blockIdx.x;
  if (bid < 6144) {
    int seg = bid >> 11;
    int i = (bid & 2047) * 256 + threadIdx.x;
    const float* in = seg == 0 ? q : (seg == 1 ? k : v);
    u16* out = seg == 0 ? qb : (seg == 1 ? kb : vb);
    const f32x4* p = (const f32x4*)(in + (size_t)i * 8);
    f32x4 a = p[0], b = p[1];
    union { u16 u[8]; f32x4 v; } o;
#pragma unroll
    for (int j = 0; j < 4; ++j) { o.u[j] = f2b(a[j]); o.u[4 + j] = f2b(b[j]); }
    *(f32x4*)(out + (size_t)i * 8) = o.v;
    return;
  }
  if (bid < 6400) {
    int idx = (bid - 6144) * 256 + threadIdx.x;  // t*32 + j
    int t = idx >> 5, j = idx & 31;
    float theta = (float)j * (1.0f / 32.0f);
    float denom = expf(theta * 9.210340371976184f);  // 10000^theta
    float invf = 1.0f / (denom + 1e-8f);
    float ang = (float)t * invf;
    tbl[idx] = (f32x2){cosf(ang), sinf(ang)};
    return;
  }
  int w = bid - 6400;
  if (w < 4096)      trans_body2(Wq, WqT, 2048, 2048, w & 63, w >> 6);
  else if (w < 6144) { w -= 4096; trans_body2(Wk, WkT, 2048, 1024, w & 31, w >> 5); }
  else if (w < 8192) { w -= 6144; trans_body2(Wv, WvT, 2048, 1024, w & 31, w >> 5); }
  else               { w -= 8192; trans_body2(Wo, WoT, 2048, 2048, w & 63, w >> 6); }
}

// ---------------- GEMM body: 128x128 tile, BK=64, fused epilogues -------------
// Prefetch-double-buffered (attn/m97 T3-minimum skeleton): STAGE(next) is
// issued right after the barrier, then compute(cur) — loads get a full compute
// phase to land instead of being drained immediately.
// smem layout (u16 elems): As0@0 Bs0@8192 As1@16384 Bs1@24576 (64KB total).
// MODE 0: plain f32 C[M][N]
// MODE 1: RoPE (interleaved pairs via shfl_xor(1), table cos/sin) -> bf16
//         head-major Oh[ncol>>6][t][64]; even lanes store packed u32 pairs.
// MODE 2: V permuted transpose -> bf16 Vt[dv][2048]; within each 32-key block
//         position p = 8g + 4(i&1) + r (r-contiguous -> one 8B store per quad).
template <int MODE>
__device__ __forceinline__ void gemm_body(u16* smem,
                                          const u16* __restrict__ A,
                                          const u16* __restrict__ Bt,
                                          void* __restrict__ Cout,
                                          const f32x2* __restrict__ tbl,
                                          float scale,
                                          int N, int K, int bx, int by) {
  const int tid = threadIdx.x;
  const int lane = tid & 63;
  const int wave = tid >> 6;
  const int m0 = by * 128;
  const int n0 = bx * 128;
  const int wm = (wave >> 1) * 64;
  const int wn = (wave & 1) * 64;
  const int g = lane >> 4, c = lane & 15;

  f32x4 acc[4][4];
#pragma unroll
  for (int i = 0; i < 4; ++i)
#pragma unroll
    for (int j = 0; j < 4; ++j) acc[i][j] = (f32x4){0.f, 0.f, 0.f, 0.f};

#define GSTAGE(aOff, bOff, k0)                                                  \
  do {                                                                          \
    _Pragma("unroll") for (int it = 0; it < 4; ++it) {                          \
      int gi = it * 256 + tid;                                                  \
      int R = gi >> 3;                                                          \
      int lg = (gi & 7) ^ (R & 7);                                              \
      gll16(A + (size_t)(m0 + R) * K + (k0) + lg * 8, smem + (aOff) + gi * 8);  \
      gll16(Bt + (size_t)(n0 + R) * K + (k0) + lg * 8, smem + (bOff) + gi * 8); \
    }                                                                           \
  } while (0)

#define GCOMP(aOff, bOff)                                                       \
  do {                                                                          \
    _Pragma("unroll") for (int kk = 0; kk < 2; ++kk) {                          \
      bf16x8 af[4], bf[4];                                                      \
      _Pragma("unroll") for (int i = 0; i < 4; ++i) {                           \
        int ph = ((kk * 4 + g) ^ (c & 7)) * 8;                                  \
        af[i] = *(const bf16x8*)&smem[(aOff) + (wm + i * 16 + c) * 64 + ph];    \
        bf[i] = *(const bf16x8*)&smem[(bOff) + (wn + i * 16 + c) * 64 + ph];    \
      }                                                                         \
      _Pragma("unroll") for (int i = 0; i < 4; ++i)                             \
        _Pragma("unroll") for (int j = 0; j < 4; ++j)                           \
          acc[i][j] = mfma16(af[i], bf[j], acc[i][j]);                          \
    }                                                                           \
  } while (0)

  const int NT = K / 64;
  GSTAGE(0, 8192, 0);
#pragma unroll 1
  for (int t = 0; t < NT; t += 2) {
    __syncthreads();  // buf0 staged (issued a full phase ago); buf1 consumed
    GSTAGE(16384, 24576, (t + 1) * 64);
    GCOMP(0, 8192);
    __syncthreads();  // buf1 staged; buf0 consumed
    if (t + 2 < NT) GSTAGE(0, 8192, (t + 2) * 64);
    GCOMP(16384, 24576);
  }
#undef GSTAGE
#undef GCOMP

  if constexpr (MODE == 0) {
    float* C = (float*)Cout;
#pragma unroll
    for (int i = 0; i < 4; ++i)
#pragma unroll
      for (int j = 0; j < 4; ++j) {
        int mrow = m0 + wm + i * 16 + g * 4;
        int ncol = n0 + wn + j * 16 + c;
#pragma unroll
        for (int r = 0; r < 4; ++r) C[(size_t)(mrow + r) * N + ncol] = acc[i][j][r];
      }
  } else if constexpr (MODE == 1) {
    u16* Oh = (u16*)Cout;
    const bool even = (c & 1) == 0;
#pragma unroll
    for (int i = 0; i < 4; ++i)
#pragma unroll
      for (int j = 0; j < 4; ++j) {
        int mrow = m0 + wm + i * 16 + g * 4;
        int ncol = n0 + wn + j * 16 + c;
        int hh = ncol >> 6;
        int d = ncol & 63;
        int jd = d >> 1;
        f32x4 own = acc[i][j];
        f32x4 part;
#pragma unroll
        for (int r = 0; r < 4; ++r) part[r] = __shfl_xor(own[r], 1);
        if (even) {
#pragma unroll
          for (int r = 0; r < 4; ++r) {
            f32x2 cs = tbl[(mrow + r) * 32 + jd];
            float o1 = (own[r] * cs[0] - part[r] * cs[1]) * scale;
            float o2 = (own[r] * cs[1] + part[r] * cs[0]) * scale;
            u32 pk = (u32)f2b(o1) | ((u32)f2b(o2) << 16);
            *(u32*)&Oh[((size_t)hh * 2048 + mrow + r) * 64 + d] = pk;
          }
        }
      }
  } else {
    u16* Vt = (u16*)Cout;
#pragma unroll
    for (int i = 0; i < 4; ++i)
#pragma unroll
      for (int j = 0; j < 4; ++j) {
        int ncol = n0 + wn + j * 16 + c;              // dv
        int tblk = (m0 + wm + i * 16) >> 5;           // 32-key block
        int p0 = 8 * g + 4 * (i & 1);                 // permuted base, +r contiguous
        u32x2 pk;
        pk[0] = (u32)f2b(acc[i][j][0]) | ((u32)f2b(acc[i][j][1]) << 16);
        pk[1] = (u32)f2b(acc[i][j][2]) | ((u32)f2b(acc[i][j][3]) << 16);
        *(u32x2*)&Vt[(size_t)ncol * 2048 + tblk * 32 + p0] = pk;
      }
  }
}

// ------- GEMM body: 128x64 tile, BK=64, prefetch-dbuf, plain f32 epilogue -----
// smem layout (u16 elems): As0@0 Bs0@8192 As1@12288 Bs1@20480 (48KB total).
__device__ __forceinline__ void gemm_body64(u16* smem,
                                            const u16* __restrict__ A,
                                            const u16* __restrict__ Bt,
                                            float* __restrict__ C,
                                            int N, int K, int bx, int by) {
  const int tid = threadIdx.x;
  const int lane = tid & 63;
  const int wave = tid >> 6;
  const int m0 = by * 128;
  const int n0 = bx * 64;
  const int wm = (wave >> 1) * 64;
  const int wn = (wave & 1) * 32;
  const int g = lane >> 4, c = lane & 15;

  f32x4 acc[4][2];
#pragma unroll
  for (int i = 0; i < 4; ++i)
#pragma unroll
    for (int j = 0; j < 2; ++j) acc[i][j] = (f32x4){0.f, 0.f, 0.f, 0.f};

#define G64STAGE(aOff, bOff, k0)                                                \
  do {                                                                          \
    _Pragma("unroll") for (int it = 0; it < 4; ++it) {                          \
      int gi = it * 256 + tid;                                                  \
      int R = gi >> 3;                                                          \
      int lg = (gi & 7) ^ (R & 7);                                              \
      gll16(A + (size_t)(m0 + R) * K + (k0) + lg * 8, smem + (aOff) + gi * 8);  \
    }                                                                           \
    _Pragma("unroll") for (int it = 0; it < 2; ++it) {                          \
      int gi = it * 256 + tid;                                                  \
      int R = gi >> 3;                                                          \
      int lg = (gi & 7) ^ (R & 7);                                              \
      gll16(Bt + (size_t)(n0 + R) * K + (k0) + lg * 8, smem + (bOff) + gi * 8); \
    }                                                                           \
  } while (0)

#define G64COMP(aOff, bOff)                                                     \
  do {                                                                          \
    _Pragma("unroll") for (int kk = 0; kk < 2; ++kk) {                          \
      bf16x8 af[4], bf[2];                                                      \
      int ph = ((kk * 4 + g) ^ (c & 7)) * 8;                                    \
      _Pragma("unroll") for (int i = 0; i < 4; ++i)                             \
        af[i] = *(const bf16x8*)&smem[(aOff) + (wm + i * 16 + c) * 64 + ph];    \
      _Pragma("unroll") for (int j = 0; j < 2; ++j)                             \
        bf[j] = *(const bf16x8*)&smem[(bOff) + (wn + j * 16 + c) * 64 + ph];    \
      _Pragma("unroll") for (int i = 0; i < 4; ++i)                             \
        _Pragma("unroll") for (int j = 0; j < 2; ++j)                           \
          acc[i][j] = mfma16(af[i], bf[j], acc[i][j]);                          \
    }                                                                           \
  } while (0)

  const int NT = K / 64;
  G64STAGE(0, 8192, 0);
#pragma unroll 1
  for (int t = 0; t < NT; t += 2) {
    __syncthreads();
    G64STAGE(12288, 20480, (t + 1) * 64);
    G64COMP(0, 8192);
    __syncthreads();
    if (t + 2 < NT) G64STAGE(0, 8192, (t + 2) * 64);
    G64COMP(12288, 20480);
  }
#undef G64STAGE
#undef G64COMP

#pragma unroll
  for (int i = 0; i < 4; ++i)
#pragma unroll
    for (int j = 0; j < 2; ++j) {
      int mrow = m0 + wm + i * 16 + g * 4;
      int ncol = n0 + wn + j * 16 + c;
#pragma unroll
      for (int r = 0; r < 4; ++r) C[(size_t)(mrow + r) * N + ncol] = acc[i][j][r];
    }
}

// fused q/k/v projections + RoPE + V-transpose epilogues: 512 blocks (2/CU)
__global__ __launch_bounds__(256, 2) void gemm_qkv_kernel(
    const u16* __restrict__ qb, const u16* __restrict__ WqT, u16* __restrict__ Qh,
    const u16* __restrict__ kb, const u16* __restrict__ WkT, u16* __restrict__ Kh,
    const u16* __restrict__ vb, const u16* __restrict__ WvT, u16* __restrict__ Vt,
    const f32x2* __restrict__ tbl) {
  __shared__ u16 smem[32768];  // 64KB: As0/Bs0/As1/Bs1
  // XCD-aware swizzle: 512 blocks, 64 consecutive work-ids per XCD
  int bid = ((blockIdx.x & 7) << 6) | (blockIdx.x >> 3);
  if (bid < 256) {
    gemm_body<1>(smem, qb, WqT, Qh, tbl, Q_SCALE, 2048, 2048, bid & 15, bid >> 4);
  } else if (bid < 384) {
    int t = bid - 256;
    gemm_body<1>(smem, kb, WkT, Kh, tbl, 1.0f, 1024, 2048, t & 7, t >> 3);
  } else {
    int t = bid - 384;
    gemm_body<2>(smem, vb, WvT, Vt, tbl, 1.0f, 1024, 2048, t & 7, t >> 3);
  }
}

// out-projection: 128x64 tiles -> 512 blocks (2 blocks/CU)
__global__ __launch_bounds__(256, 2) void gemm_one_kernel(const u16* __restrict__ A,
                                                          const u16* __restrict__ Bt,
                                                          float* __restrict__ C) {
  __shared__ u16 smem[24576];  // 48KB
  int bid = ((blockIdx.x & 7) << 6) | (blockIdx.x >> 3);  // 512 blocks
  gemm_body64(smem, A, Bt, C, 2048, 2048, bid & 31, bid >> 5);
}

// ---------------- fused differential flash attention (R10, frozen) ------------
// 2-tile mega-phases, 4 LDS tile-slots (96KB), permuted-Vt single-b128 PV
// fragments (conflicts 0), raw v_exp_f32, setprio around PV.
__global__ __launch_bounds__(512, 2) void attn_kernel(const u16* __restrict__ Qb,
                                                      const u16* __restrict__ Kb,
                                                      const u16* __restrict__ Vt,
                                                      u16* __restrict__ AO,
                                                      const float* __restrict__ lq1,
                                                      const float* __restrict__ lk1,
                                                      const float* __restrict__ lq2,
                                                      const float* __restrict__ lk2,
                                                      const float* __restrict__ subln) {
  // XCD swizzle: 32 consecutive work-ids (2 heads) per XCD's L2
  const int b = ((blockIdx.x & 7) << 5) | (blockIdx.x >> 3);
  const int h = b >> 4;
  const int tid = threadIdx.x;
  const int wave = tid >> 6;
  const int lane = tid & 63;
  const int t0 = ((b & 15) * 8 + wave) * 16;
  const int g = lane >> 4, c = lane & 15;
  const int c7 = c & 7;

  __shared__ u16 smem[49152];  // 96KB: K slots 0/4096/8192/12288, V 16384/24576/32768/40960

  const u16* Kh = Kb + (size_t)h * 2048 * 64;
  const u16* Vh = Vt + (size_t)(h >> 1) * 128 * 2048;

  // lambda (wave-parallel)
  float myl1 = lq1[lane] * lk1[lane];
  float myl2 = lq2[lane] * lk2[lane];
#pragma unroll
  for (int off = 32; off; off >>= 1) {
    myl1 += __shfl_xor(myl1, off);
    myl2 += __shfl_xor(myl2, off);
  }
  const float lambda_full = expf(myl1) - expf(myl2) + LAMBDA_INIT_F;

  // Q fragments (B-operand: col = q-row = c, natural d-slots)
  bf16x8 qf[2][2];
#pragma unroll
  for (int e = 0; e < 2; ++e)
#pragma unroll
    for (int d = 0; d < 2; ++d)
      qf[e][d] = *(const bf16x8*)(Qb + ((size_t)(2 * h + e) * 2048 + t0 + c) * 64 + d * 32 + g * 8);

  // loop-invariant LDS read bases (u16-elem units); shared by K and V reads
  const int kb0 = c * 64 + ((g ^ c7) * 8);
  const int kb1 = kb0 ^ 32;

  // per-thread stage source bases (granule-XOR pre-swizzled)
  const u16* ksrc0;
  const u16* vsrc0;
  const u16* vsrc1;
  { int gi = tid;       int R = gi >> 3; ksrc0 = Kh + R * 64 + ((gi & 7) ^ (R & 7)) * 8; }
  { int gi = tid;       int R = gi >> 3; vsrc0 = Vh + (size_t)R * 2048 + ((gi & 7) ^ (R & 7)) * 8; }
  { int gi = 512 + tid; int R = gi >> 3; vsrc1 = Vh + (size_t)R * 2048 + ((gi & 7) ^ (R & 7)) * 8; }

  f32x4 O[2][8];
#pragma unroll
  for (int e = 0; e < 2; ++e)
#pragma unroll
    for (int f = 0; f < 8; ++f) O[e][f] = (f32x4){0.f, 0.f, 0.f, 0.f};
  float m0 = -1e30f, m1 = -1e30f, ls0 = 0.f, ls1 = 0.f;

// stage 128 keys (2 tiles) into slot pair (kOffA/kOffB, vOffA/vOffB)
#define STAGE2(kOffA, kOffB, vOffA, vOffB, s0)                          \
  do {                                                                  \
    gll16(ksrc0 + (size_t)(s0) * 64, smem + (kOffA) + tid * 8);         \
    gll16(ksrc0 + (size_t)((s0) + 64) * 64, smem + (kOffB) + tid * 8);  \
    gll16(vsrc0 + (s0), smem + (vOffA) + tid * 8);                      \
    gll16(vsrc1 + (s0), smem + (vOffA) + 4096 + tid * 8);               \
    gll16(vsrc0 + (s0) + 64, smem + (vOffB) + tid * 8);                 \
    gll16(vsrc1 + (s0) + 64, smem + (vOffB) + 4096 + tid * 8);          \
  } while (0)

#define TILE(kOff, vOff)                                                      \
  do {                                                                        \
    bf16x8 kf[4][2];                                                          \
    _Pragma("unroll") for (int sf = 0; sf < 4; ++sf) {                        \
      kf[sf][0] = *(const bf16x8*)&smem[(kOff) + kb0 + sf * 1024];            \
      kf[sf][1] = *(const bf16x8*)&smem[(kOff) + kb1 + sf * 1024];            \
    }                                                                         \
    f32x4 sa[2][4];                                                           \
    _Pragma("unroll") for (int e = 0; e < 2; ++e)                             \
      _Pragma("unroll") for (int sf = 0; sf < 4; ++sf) {                      \
        f32x4 z = (f32x4){0.f, 0.f, 0.f, 0.f};                                \
        z = mfma16(kf[sf][0], qf[e][0], z);                                   \
        z = mfma16(kf[sf][1], qf[e][1], z);                                   \
        sa[e][sf] = z;                                                        \
      }                                                                       \
    bf16x8 vv0[8];                                                            \
    _Pragma("unroll") for (int f = 0; f < 8; ++f)                             \
      vv0[f] = *(const bf16x8*)&smem[(vOff) + kb0 + f * 1024];                \
    bf16x8 paf[2][2];                                                         \
    _Pragma("unroll") for (int e = 0; e < 2; ++e) {                           \
      float& m_e = e ? m1 : m0;                                               \
      float& ls_e = e ? ls1 : ls0;                                            \
      float mx = sa[e][0][0];                                                 \
      _Pragma("unroll") for (int sf = 0; sf < 4; ++sf)                        \
        _Pragma("unroll") for (int r = 0; r < 4; ++r)                         \
          mx = fmaxf(mx, sa[e][sf][r]);                                       \
      mx = fmaxf(mx, __shfl_xor(mx, 16));                                     \
      mx = fmaxf(mx, __shfl_xor(mx, 32));                                     \
      if (__any(mx > m_e + THR_LOG2)) {                                       \
        float mn = fmaxf(m_e, mx);                                            \
        float sc = fexp2(m_e - mn);                                           \
        m_e = mn;                                                             \
        ls_e *= sc;                                                           \
        float scr[4];                                                         \
        _Pragma("unroll") for (int r = 0; r < 4; ++r) scr[r] = __shfl(sc, g * 4 + r); \
        _Pragma("unroll") for (int ff = 0; ff < 8; ++ff)                      \
          _Pragma("unroll") for (int r = 0; r < 4; ++r) O[e][ff][r] *= scr[r]; \
      }                                                                       \
      float p[4][4];                                                          \
      float sum = 0.f;                                                        \
      _Pragma("unroll") for (int sf = 0; sf < 4; ++sf)                        \
        _Pragma("unroll") for (int r = 0; r < 4; ++r) {                       \
          float pv = fexp2(sa[e][sf][r] - m_e);                               \
          p[sf][r] = pv;                                                      \
          sum += pv;                                                          \
        }                                                                     \
      sum += __shfl_xor(sum, 16);                                             \
      sum += __shfl_xor(sum, 32);                                             \
      ls_e += sum;                                                            \
      paf[e][0] = (bf16x8){(__bf16)p[0][0], (__bf16)p[0][1], (__bf16)p[0][2], (__bf16)p[0][3], \
                           (__bf16)p[1][0], (__bf16)p[1][1], (__bf16)p[1][2], (__bf16)p[1][3]}; \
      paf[e][1] = (bf16x8){(__bf16)p[2][0], (__bf16)p[2][1], (__bf16)p[2][2], (__bf16)p[2][3], \
                           (__bf16)p[3][0], (__bf16)p[3][1], (__bf16)p[3][2], (__bf16)p[3][3]}; \
    }                                                                         \
    __builtin_amdgcn_s_setprio(1);                                            \
    bf16x8 vv1[8];                                                            \
    _Pragma("unroll") for (int f = 0; f < 8; ++f)                             \
      vv1[f] = *(const bf16x8*)&smem[(vOff) + kb1 + f * 1024];                \
    _Pragma("unroll") for (int f = 0; f < 8; ++f) {                           \
      O[0][f] = mfma16(paf[0][0], vv0[f], O[0][f]);                           \
      O[1][f] = mfma16(paf[1][0], vv0[f], O[1][f]);                           \
    }                                                                         \
    _Pragma("unroll") for (int f = 0; f < 8; ++f) {                           \
      O[0][f] = mfma16(paf[0][1], vv1[f], O[0][f]);                           \
      O[1][f] = mfma16(paf[1][1], vv1[f], O[1][f]);                           \
    }                                                                         \
    __builtin_amdgcn_s_setprio(0);                                            \
  } while (0)

  STAGE2(0, 4096, 16384, 24576, 0);

#pragma unroll 1
  for (int t = 0; t < 16; t += 2) {
    __syncthreads();  // pair A (slots 0,1) staged; all waves done with pair B
    STAGE2(8192, 12288, 32768, 40960, (t + 1) * 128);
    TILE(0, 16384);
    TILE(4096, 24576);
    __syncthreads();  // pair B (slots 2,3) staged; all waves done with pair A
    if (t < 14) STAGE2(0, 4096, 16384, 24576, (t + 2) * 128);
    TILE(8192, 32768);
    TILE(12288, 40960);
  }

  // epilogue: redistribute 1/ls from c-layout to (g,r)-layout
  float inv0 = 1.f / ls0, inv1 = 1.f / ls1;
  float i0[4], i1[4];
#pragma unroll
  for (int r = 0; r < 4; ++r) {
    i0[r] = __shfl(inv0, g * 4 + r);
    i1[r] = __shfl(inv1, g * 4 + r);
  }
  float res[8][4];
  float ss[4] = {0.f, 0.f, 0.f, 0.f};
#pragma unroll
  for (int f = 0; f < 8; ++f)
#pragma unroll
    for (int r = 0; r < 4; ++r) {
      float vv = O[0][f][r] * i0[r] - lambda_full * (O[1][f][r] * i1[r]);
      res[f][r] = vv;
      ss[r] += vv * vv;
    }
#pragma unroll
  for (int off = 1; off < 16; off <<= 1)
#pragma unroll
    for (int r = 0; r < 4; ++r) ss[r] += __shfl_xor(ss[r], off);
  float rms[4];
#pragma unroll
  for (int r = 0; r < 4; ++r)
    rms[r] = rsqrtf(ss[r] * (1.0f / 128.0f) + 1e-5f) * ONE_MINUS_LI;
  float w[8];
#pragma unroll
  for (int f = 0; f < 8; ++f) w[f] = subln[f * 16 + c];
#pragma unroll
  for (int f = 0; f < 8; ++f)
#pragma unroll
    for (int r = 0; r < 4; ++r)
      AO[(size_t)(t0 + g * 4 + r) * 2048 + h * 128 + f * 16 + c] = f2b(res[f][r] * rms[r] * w[f]);
}

// ------------------------------------------------------------------------------
extern "C" void kernel_launch(void* const* d_in, const int* in_sizes, int n_in,
                              void* d_out, int out_size, void* d_ws, size_t ws_size,
                              hipStream_t stream) {
  const float* q     = (const float*)d_in[0];
  const float* k     = (const float*)d_in[1];
  const float* v     = (const float*)d_in[2];
  const float* Wq    = (const float*)d_in[3];
  const float* Wk    = (const float*)d_in[4];
  const float* Wv    = (const float*)d_in[5];
  const float* Wout  = (const float*)d_in[6];
  const float* lq1   = (const float*)d_in[7];
  const float* lk1   = (const float*)d_in[8];
  const float* lq2   = (const float*)d_in[9];
  const float* lk2   = (const float*)d_in[10];
  const float* subln = (const float*)d_in[11];
  float* out = (float*)d_out;

  char* ws = (char*)d_ws;
  size_t off = 0;
  auto alloc = [&](size_t bytes) -> void* {
    void* p = ws + off;
    off += (bytes + 255) & ~(size_t)255;
    return p;
  };
  u16* qb  = (u16*)alloc(2048ull * 2048 * 2);
  u16* kb  = (u16*)alloc(2048ull * 2048 * 2);
  u16* vb  = (u16*)alloc(2048ull * 2048 * 2);
  u16* WqT = (u16*)alloc(2048ull * 2048 * 2);
  u16* WkT = (u16*)alloc(1024ull * 2048 * 2);
  u16* WvT = (u16*)alloc(1024ull * 2048 * 2);
  u16* WoT = (u16*)alloc(2048ull * 2048 * 2);
  f32x2* tbl = (f32x2*)alloc(2048ull * 32 * 8);
  u16* Qh  = (u16*)alloc(32ull * 2048 * 64 * 2);
  u16* Kh  = (u16*)alloc(16ull * 2048 * 64 * 2);
  u16* Vt  = (u16*)alloc(1024ull * 2048 * 2);
  u16* AO  = (u16*)alloc(2048ull * 2048 * 2);

  // 1. fused prep: cast q/k/v + rope table + all weight transposes (one launch)
  prep_kernel<<<18688, 256, 0, stream>>>(q, k, v, qb, kb, vb, tbl,
                                         Wq, WqT, Wk, WkT, Wv, WvT, Wout, WoT);
  // 2. projections + fused RoPE (Q,K) + fused permuted V-transpose (one launch)
  gemm_qkv_kernel<<<512, 256, 0, stream>>>(qb, WqT, Qh, kb, WkT, Kh, vb, WvT, Vt, tbl);
  // 3. differential flash attention -> AO bf16 [2048][2048]
  attn_kernel<<<256, 512, 0, stream>>>(Qh, Kh, Vt, AO, lq1, lk1, lq2, lk2, subln);
  // 4. output projection -> f32 d_out (128x64 tiles, 2 blocks/CU)
  gemm_one_kernel<<<512, 256, 0, stream>>>(AO, WoT, out);
}

// Round 12
// 140.827 us; speedup vs baseline: 1.1293x; 1.0139x over previous
//
#include <hip/hip_runtime.h>

typedef unsigned short u16;
typedef unsigned int u32;
typedef float f32x4 __attribute__((ext_vector_type(4)));
typedef float f32x2 __attribute__((ext_vector_type(2)));
typedef unsigned int u32x2 __attribute__((ext_vector_type(2)));
typedef __bf16 bf16x8 __attribute__((ext_vector_type(8)));
typedef __bf16 bf16x4 __attribute__((ext_vector_type(4)));

#define LAMBDA_INIT_F 0.7836057665316245f
#define ONE_MINUS_LI  0.2163942334683755f
#define THR_LOG2 11.0f
// 0.125 * log2(e): fold softmax base-2 conversion into Q scaling
#define Q_SCALE 0.18033688011112042f

__device__ __forceinline__ u16 f2b(float f) {
  union { float f; u32 u; } x; x.f = f;
  u32 r = x.u + 0x7fffu + ((x.u >> 16) & 1u);
  return (u16)(r >> 16);
}

__device__ __forceinline__ f32x4 mfma16(bf16x8 a, bf16x8 b, f32x4 c) {
  return __builtin_amdgcn_mfma_f32_16x16x32_bf16(a, b, c, 0, 0, 0);
}

__device__ __forceinline__ float fexp2(float x) { return __builtin_amdgcn_exp2f(x); }
__device__ __forceinline__ float max3(float a, float b, float c) {
  return fmaxf(fmaxf(a, b), c);  // clang fuses to v_max3_f32
}

// async global->LDS, 16B per lane; LDS dest must be linear in lane order
__device__ __forceinline__ void gll16(const void* gp, void* lp) {
  __builtin_amdgcn_global_load_lds((__attribute__((address_space(1))) void*)(gp),
                                   (__attribute__((address_space(3))) void*)(lp),
                                   16, 0, 0);
}

// ------------- tiled transpose+cast body: f32 [R][C] -> bf16 [C][R] -----------
__device__ __forceinline__ void trans_body2(const float* __restrict__ in,
                                            u16* __restrict__ out, int R, int C,
                                            int bxb, int byb) {
  __shared__ float tile[32][33];
  int bx = bxb * 32;  // col base
  int by = byb * 32;  // row base
  int tx = threadIdx.x & 31, ty = threadIdx.x >> 5;
#pragma unroll
  for (int i = 0; i < 32; i += 8)
    tile[ty + i][tx] = in[(size_t)(by + ty + i) * C + bx + tx];
  __syncthreads();
#pragma unroll
  for (int i = 0; i < 32; i += 8)
    out[(size_t)(bx + ty + i) * R + by + tx] = f2b(tile[tx][ty + i]);
}

// --- fused prep: cast q/k/v -> bf16, rope cos/sin table, 4 weight transposes --
// grid 1D: [0,6144) cast, [6144,6400) table, [6400,18688) wtrans
__global__ __launch_bounds__(256) void prep_kernel(
    const float* __restrict__ q, const float* __restrict__ k, const float* __restrict__ v,
    u16* __restrict__ qb, u16* __restrict__ kb, u16* __restrict__ vb,
    f32x2* __restrict__ tbl,
    const float* __restrict__ Wq, u16* __restrict__ WqT,
    const float* __restrict__ Wk, u16* __restrict__ WkT,
    const float* __restrict__ Wv, u16* __restrict__ WvT,
    const float* __restrict__ Wo, u16* __restrict__ WoT) {
  int bid = blockIdx.x;
  if (bid < 6144) {
    int seg = bid >> 11;
    int i = (bid & 2047) * 256 + threadIdx.x;
    const float* in = seg == 0 ? q : (seg == 1 ? k : v);
    u16* out = seg == 0 ? qb : (seg == 1 ? kb : vb);
    const f32x4* p = (const f32x4*)(in + (size_t)i * 8);
    f32x4 a = p[0], b = p[1];
    union { u16 u[8]; f32x4 v; } o;
#pragma unroll
    for (int j = 0; j < 4; ++j) { o.u[j] = f2b(a[j]); o.u[4 + j] = f2b(b[j]); }
    *(f32x4*)(out + (size_t)i * 8) = o.v;
    return;
  }
  if (bid < 6400) {
    int idx = (bid - 6144) * 256 + threadIdx.x;  // t*32 + j
    int t = idx >> 5, j = idx & 31;
    float theta = (float)j * (1.0f / 32.0f);
    float denom = expf(theta * 9.210340371976184f);  // 10000^theta
    float invf = 1.0f / (denom + 1e-8f);
    float ang = (float)t * invf;
    tbl[idx] = (f32x2){cosf(ang), sinf(ang)};
    return;
  }
  int w = bid - 6400;
  if (w < 4096)      trans_body2(Wq, WqT, 2048, 2048, w & 63, w >> 6);
  else if (w < 6144) { w -= 4096; trans_body2(Wk, WkT, 2048, 1024, w & 31, w >> 5); }
  else if (w < 8192) { w -= 6144; trans_body2(Wv, WvT, 2048, 1024, w & 31, w >> 5); }
  else               { w -= 8192; trans_body2(Wo, WoT, 2048, 2048, w & 63, w >> 6); }
}

// ---------------- GEMM body: 128x128 tile, BK=64, fused epilogues -------------
// Prefetch-double-buffered (attn/m97 T3-minimum skeleton).
// smem layout (u16 elems): As0@0 Bs0@8192 As1@16384 Bs1@24576 (64KB total).
// MODE 0: plain f32 C[M][N]
// MODE 1: RoPE epilogue -> bf16 head-major Oh[ncol>>6][t][64]. Lane pair (c,c^1)
//         handles one column pair: even lane rows 0-1, odd lane rows 2-3
//         (halves epilogue VALU+stores vs even-only).
// MODE 2: V permuted transpose -> bf16 Vt[dv][2048]; within each 32-key block
//         position p = 8g + 4(i&1) + r (r-contiguous -> one 8B store per quad).
template <int MODE>
__device__ __forceinline__ void gemm_body(u16* smem,
                                          const u16* __restrict__ A,
                                          const u16* __restrict__ Bt,
                                          void* __restrict__ Cout,
                                          const f32x2* __restrict__ tbl,
                                          float scale,
                                          int N, int K, int bx, int by) {
  const int tid = threadIdx.x;
  const int lane = tid & 63;
  const int wave = tid >> 6;
  const int m0 = by * 128;
  const int n0 = bx * 128;
  const int wm = (wave >> 1) * 64;
  const int wn = (wave & 1) * 64;
  const int g = lane >> 4, c = lane & 15;

  f32x4 acc[4][4];
#pragma unroll
  for (int i = 0; i < 4; ++i)
#pragma unroll
    for (int j = 0; j < 4; ++j) acc[i][j] = (f32x4){0.f, 0.f, 0.f, 0.f};

#define GSTAGE(aOff, bOff, k0)                                                  \
  do {                                                                          \
    _Pragma("unroll") for (int it = 0; it < 4; ++it) {                          \
      int gi = it * 256 + tid;                                                  \
      int R = gi >> 3;                                                          \
      int lg = (gi & 7) ^ (R & 7);                                              \
      gll16(A + (size_t)(m0 + R) * K + (k0) + lg * 8, smem + (aOff) + gi * 8);  \
      gll16(Bt + (size_t)(n0 + R) * K + (k0) + lg * 8, smem + (bOff) + gi * 8); \
    }                                                                           \
  } while (0)

#define GCOMP(aOff, bOff)                                                       \
  do {                                                                          \
    _Pragma("unroll") for (int kk = 0; kk < 2; ++kk) {                          \
      bf16x8 af[4], bf[4];                                                      \
      _Pragma("unroll") for (int i = 0; i < 4; ++i) {                           \
        int ph = ((kk * 4 + g) ^ (c & 7)) * 8;                                  \
        af[i] = *(const bf16x8*)&smem[(aOff) + (wm + i * 16 + c) * 64 + ph];    \
        bf[i] = *(const bf16x8*)&smem[(bOff) + (wn + i * 16 + c) * 64 + ph];    \
      }                                                                         \
      _Pragma("unroll") for (int i = 0; i < 4; ++i)                             \
        _Pragma("unroll") for (int j = 0; j < 4; ++j)                           \
          acc[i][j] = mfma16(af[i], bf[j], acc[i][j]);                          \
    }                                                                           \
  } while (0)

  const int NT = K / 64;
  GSTAGE(0, 8192, 0);
#pragma unroll 1
  for (int t = 0; t < NT; t += 2) {
    __syncthreads();  // buf0 staged (issued a full phase ago); buf1 consumed
    GSTAGE(16384, 24576, (t + 1) * 64);
    GCOMP(0, 8192);
    __syncthreads();  // buf1 staged; buf0 consumed
    if (t + 2 < NT) GSTAGE(0, 8192, (t + 2) * 64);
    GCOMP(16384, 24576);
  }
#undef GSTAGE
#undef GCOMP

  if constexpr (MODE == 0) {
    float* C = (float*)Cout;
#pragma unroll
    for (int i = 0; i < 4; ++i)
#pragma unroll
      for (int j = 0; j < 4; ++j) {
        int mrow = m0 + wm + i * 16 + g * 4;
        int ncol = n0 + wn + j * 16 + c;
#pragma unroll
        for (int r = 0; r < 4; ++r) C[(size_t)(mrow + r) * N + ncol] = acc[i][j][r];
      }
  } else if constexpr (MODE == 1) {
    u16* Oh = (u16*)Cout;
    const bool even = (c & 1) == 0;
    const int rbase = (c & 1) * 2;  // even lane rows 0-1, odd lane rows 2-3
#pragma unroll
    for (int i = 0; i < 4; ++i)
#pragma unroll
      for (int j = 0; j < 4; ++j) {
        int mrow = m0 + wm + i * 16 + g * 4;
        int ncol = n0 + wn + j * 16 + c;
        int hh = ncol >> 6;
        int d = ncol & 63;
        int jd = d >> 1;        // same for both parities (d even / d odd pair)
        int dst = d & ~1;       // column-pair base
        f32x4 own = acc[i][j];
        f32x4 part;
#pragma unroll
        for (int r = 0; r < 4; ++r) part[r] = __shfl_xor(own[r], 1);
#pragma unroll
        for (int rr = 0; rr < 2; ++rr) {
          int r = rbase + rr;
          float x1 = even ? own[r] : part[r];  // value at even col of pair
          float x2 = even ? part[r] : own[r];  // value at odd col of pair
          f32x2 cs = tbl[(mrow + r) * 32 + jd];
          float o1 = (x1 * cs[0] - x2 * cs[1]) * scale;
          float o2 = (x1 * cs[1] + x2 * cs[0]) * scale;
          u32 pk = (u32)f2b(o1) | ((u32)f2b(o2) << 16);
          *(u32*)&Oh[((size_t)hh * 2048 + mrow + r) * 64 + dst] = pk;
        }
      }
  } else {
    u16* Vt = (u16*)Cout;
#pragma unroll
    for (int i = 0; i < 4; ++i)
#pragma unroll
      for (int j = 0; j < 4; ++j) {
        int ncol = n0 + wn + j * 16 + c;              // dv
        int tblk = (m0 + wm + i * 16) >> 5;           // 32-key block
        int p0 = 8 * g + 4 * (i & 1);                 // permuted base, +r contiguous
        u32x2 pk;
        pk[0] = (u32)f2b(acc[i][j][0]) | ((u32)f2b(acc[i][j][1]) << 16);
        pk[1] = (u32)f2b(acc[i][j][2]) | ((u32)f2b(acc[i][j][3]) << 16);
        *(u32x2*)&Vt[(size_t)ncol * 2048 + tblk * 32 + p0] = pk;
      }
  }
}

// ------- GEMM body: 128x64 tile, BK=64, prefetch-dbuf, plain f32 epilogue -----
// smem layout (u16 elems): As0@0 Bs0@8192 As1@12288 Bs1@20480 (48KB total).
__device__ __forceinline__ void gemm_body64(u16* smem,
                                            const u16* __restrict__ A,
                                            const u16* __restrict__ Bt,
                                            float* __restrict__ C,
                                            int N, int K, int bx, int by) {
  const int tid = threadIdx.x;
  const int lane = tid & 63;
  const int wave = tid >> 6;
  const int m0 = by * 128;
  const int n0 = bx * 64;
  const int wm = (wave >> 1) * 64;
  const int wn = (wave & 1) * 32;
  const int g = lane >> 4, c = lane & 15;

  f32x4 acc[4][2];
#pragma unroll
  for (int i = 0; i < 4; ++i)
#pragma unroll
    for (int j = 0; j < 2; ++j) acc[i][j] = (f32x4){0.f, 0.f, 0.f, 0.f};

#define G64STAGE(aOff, bOff, k0)                                                \
  do {                                                                          \
    _Pragma("unroll") for (int it = 0; it < 4; ++it) {                          \
      int gi = it * 256 + tid;                                                  \
      int R = gi >> 3;                                                          \
      int lg = (gi & 7) ^ (R & 7);                                              \
      gll16(A + (size_t)(m0 + R) * K + (k0) + lg * 8, smem + (aOff) + gi * 8);  \
    }                                                                           \
    _Pragma("unroll") for (int it = 0; it < 2; ++it) {                          \
      int gi = it * 256 + tid;                                                  \
      int R = gi >> 3;                                                          \
      int lg = (gi & 7) ^ (R & 7);                                              \
      gll16(Bt + (size_t)(n0 + R) * K + (k0) + lg * 8, smem + (bOff) + gi * 8); \
    }                                                                           \
  } while (0)

#define G64COMP(aOff, bOff)                                                     \
  do {                                                                          \
    _Pragma("unroll") for (int kk = 0; kk < 2; ++kk) {                          \
      bf16x8 af[4], bf[2];                                                      \
      int ph = ((kk * 4 + g) ^ (c & 7)) * 8;                                    \
      _Pragma("unroll") for (int i = 0; i < 4; ++i)                             \
        af[i] = *(const bf16x8*)&smem[(aOff) + (wm + i * 16 + c) * 64 + ph];    \
      _Pragma("unroll") for (int j = 0; j < 2; ++j)                             \
        bf[j] = *(const bf16x8*)&smem[(bOff) + (wn + j * 16 + c) * 64 + ph];    \
      _Pragma("unroll") for (int i = 0; i < 4; ++i)                             \
        _Pragma("unroll") for (int j = 0; j < 2; ++j)                           \
          acc[i][j] = mfma16(af[i], bf[j], acc[i][j]);                          \
    }                                                                           \
  } while (0)

  const int NT = K / 64;
  G64STAGE(0, 8192, 0);
#pragma unroll 1
  for (int t = 0; t < NT; t += 2) {
    __syncthreads();
    G64STAGE(12288, 20480, (t + 1) * 64);
    G64COMP(0, 8192);
    __syncthreads();
    if (t + 2 < NT) G64STAGE(0, 8192, (t + 2) * 64);
    G64COMP(12288, 20480);
  }
#undef G64STAGE
#undef G64COMP

#pragma unroll
  for (int i = 0; i < 4; ++i)
#pragma unroll
    for (int j = 0; j < 2; ++j) {
      int mrow = m0 + wm + i * 16 + g * 4;
      int ncol = n0 + wn + j * 16 + c;
#pragma unroll
      for (int r = 0; r < 4; ++r) C[(size_t)(mrow + r) * N + ncol] = acc[i][j][r];
    }
}

// fused q/k/v projections + RoPE + V-transpose epilogues: 512 blocks (2/CU)
__global__ __launch_bounds__(256, 2) void gemm_qkv_kernel(
    const u16* __restrict__ qb, const u16* __restrict__ WqT, u16* __restrict__ Qh,
    const u16* __restrict__ kb, const u16* __restrict__ WkT, u16* __restrict__ Kh,
    const u16* __restrict__ vb, const u16* __restrict__ WvT, u16* __restrict__ Vt,
    const f32x2* __restrict__ tbl) {
  __shared__ u16 smem[32768];  // 64KB: As0/Bs0/As1/Bs1
  // XCD-aware swizzle: 512 blocks, 64 consecutive work-ids per XCD
  int bid = ((blockIdx.x & 7) << 6) | (blockIdx.x >> 3);
  if (bid < 256) {
    gemm_body<1>(smem, qb, WqT, Qh, tbl, Q_SCALE, 2048, 2048, bid & 15, bid >> 4);
  } else if (bid < 384) {
    int t = bid - 256;
    gemm_body<1>(smem, kb, WkT, Kh, tbl, 1.0f, 1024, 2048, t & 7, t >> 3);
  } else {
    int t = bid - 384;
    gemm_body<2>(smem, vb, WvT, Vt, tbl, 1.0f, 1024, 2048, t & 7, t >> 3);
  }
}

// out-projection: 128x64 tiles -> 512 blocks (2 blocks/CU)
__global__ __launch_bounds__(256, 2) void gemm_one_kernel(const u16* __restrict__ A,
                                                          const u16* __restrict__ Bt,
                                                          float* __restrict__ C) {
  __shared__ u16 smem[24576];  // 48KB
  int bid = ((blockIdx.x & 7) << 6) | (blockIdx.x >> 3);  // 512 blocks
  gemm_body64(smem, A, Bt, C, 2048, 2048, bid & 31, bid >> 5);
}

// ---------------- fused differential flash attention (R10 + max3/sum trees) ---
// 2-tile mega-phases, 4 LDS tile-slots (96KB), permuted-Vt single-b128 PV
// fragments (conflicts 0), raw v_exp_f32, setprio around PV.
__global__ __launch_bounds__(512, 2) void attn_kernel(const u16* __restrict__ Qb,
                                                      const u16* __restrict__ Kb,
                                                      const u16* __restrict__ Vt,
                                                      u16* __restrict__ AO,
                                                      const float* __restrict__ lq1,
                                                      const float* __restrict__ lk1,
                                                      const float* __restrict__ lq2,
                                                      const float* __restrict__ lk2,
                                                      const float* __restrict__ subln) {
  // XCD swizzle: 32 consecutive work-ids (2 heads) per XCD's L2
  const int b = ((blockIdx.x & 7) << 5) | (blockIdx.x >> 3);
  const int h = b >> 4;
  const int tid = threadIdx.x;
  const int wave = tid >> 6;
  const int lane = tid & 63;
  const int t0 = ((b & 15) * 8 + wave) * 16;
  const int g = lane >> 4, c = lane & 15;
  const int c7 = c & 7;

  __shared__ u16 smem[49152];  // 96KB: K slots 0/4096/8192/12288, V 16384/24576/32768/40960

  const u16* Kh = Kb + (size_t)h * 2048 * 64;
  const u16* Vh = Vt + (size_t)(h >> 1) * 128 * 2048;

  // lambda (wave-parallel)
  float myl1 = lq1[lane] * lk1[lane];
  float myl2 = lq2[lane] * lk2[lane];
#pragma unroll
  for (int off = 32; off; off >>= 1) {
    myl1 += __shfl_xor(myl1, off);
    myl2 += __shfl_xor(myl2, off);
  }
  const float lambda_full = expf(myl1) - expf(myl2) + LAMBDA_INIT_F;

  // Q fragments (B-operand: col = q-row = c, natural d-slots)
  bf16x8 qf[2][2];
#pragma unroll
  for (int e = 0; e < 2; ++e)
#pragma unroll
    for (int d = 0; d < 2; ++d)
      qf[e][d] = *(const bf16x8*)(Qb + ((size_t)(2 * h + e) * 2048 + t0 + c) * 64 + d * 32 + g * 8);

  // loop-invariant LDS read bases (u16-elem units); shared by K and V reads
  const int kb0 = c * 64 + ((g ^ c7) * 8);
  const int kb1 = kb0 ^ 32;

  // per-thread stage source bases (granule-XOR pre-swizzled)
  const u16* ksrc0;
  const u16* vsrc0;
  const u16* vsrc1;
  { int gi = tid;       int R = gi >> 3; ksrc0 = Kh + R * 64 + ((gi & 7) ^ (R & 7)) * 8; }
  { int gi = tid;       int R = gi >> 3; vsrc0 = Vh + (size_t)R * 2048 + ((gi & 7) ^ (R & 7)) * 8; }
  { int gi = 512 + tid; int R = gi >> 3; vsrc1 = Vh + (size_t)R * 2048 + ((gi & 7) ^ (R & 7)) * 8; }

  f32x4 O[2][8];
#pragma unroll
  for (int e = 0; e < 2; ++e)
#pragma unroll
    for (int f = 0; f < 8; ++f) O[e][f] = (f32x4){0.f, 0.f, 0.f, 0.f};
  float m0 = -1e30f, m1 = -1e30f, ls0 = 0.f, ls1 = 0.f;

// stage 128 keys (2 tiles) into slot pair (kOffA/kOffB, vOffA/vOffB)
#define STAGE2(kOffA, kOffB, vOffA, vOffB, s0)                          \
  do {                                                                  \
    gll16(ksrc0 + (size_t)(s0) * 64, smem + (kOffA) + tid * 8);         \
    gll16(ksrc0 + (size_t)((s0) + 64) * 64, smem + (kOffB) + tid * 8);  \
    gll16(vsrc0 + (s0), smem + (vOffA) + tid * 8);                      \
    gll16(vsrc1 + (s0), smem + (vOffA) + 4096 + tid * 8);               \
    gll16(vsrc0 + (s0) + 64, smem + (vOffB) + tid * 8);                 \
    gll16(vsrc1 + (s0) + 64, smem + (vOffB) + 4096 + tid * 8);          \
  } while (0)

#define TILE(kOff, vOff)                                                      \
  do {                                                                        \
    bf16x8 kf[4][2];                                                          \
    _Pragma("unroll") for (int sf = 0; sf < 4; ++sf) {                        \
      kf[sf][0] = *(const bf16x8*)&smem[(kOff) + kb0 + sf * 1024];            \
      kf[sf][1] = *(const bf16x8*)&smem[(kOff) + kb1 + sf * 1024];            \
    }                                                                         \
    f32x4 sa[2][4];                                                           \
    _Pragma("unroll") for (int e = 0; e < 2; ++e)                             \
      _Pragma("unroll") for (int sf = 0; sf < 4; ++sf) {                      \
        f32x4 z = (f32x4){0.f, 0.f, 0.f, 0.f};                                \
        z = mfma16(kf[sf][0], qf[e][0], z);                                   \
        z = mfma16(kf[sf][1], qf[e][1], z);                                   \
        sa[e][sf] = z;                                                        \
      }                                                                       \
    bf16x8 vv0[8];                                                            \
    _Pragma("unroll") for (int f = 0; f < 8; ++f)                             \
      vv0[f] = *(const bf16x8*)&smem[(vOff) + kb0 + f * 1024];                \
    bf16x8 paf[2][2];                                                         \
    _Pragma("unroll") for (int e = 0; e < 2; ++e) {                           \
      float& m_e = e ? m1 : m0;                                               \
      float& ls_e = e ? ls1 : ls0;                                            \
      float t1 = max3(sa[e][0][0], sa[e][0][1], sa[e][0][2]);                 \
      float t2 = max3(sa[e][0][3], sa[e][1][0], sa[e][1][1]);                 \
      float t3 = max3(sa[e][1][2], sa[e][1][3], sa[e][2][0]);                 \
      float t4 = max3(sa[e][2][1], sa[e][2][2], sa[e][2][3]);                 \
      float t5 = max3(sa[e][3][0], sa[e][3][1], sa[e][3][2]);                 \
      float mx = max3(t1, t2, t3);                                            \
      mx = max3(mx, t4, t5);                                                  \
      mx = fmaxf(mx, sa[e][3][3]);                                            \
      mx = fmaxf(mx, __shfl_xor(mx, 16));                                     \
      mx = fmaxf(mx, __shfl_xor(mx, 32));                                     \
      if (__any(mx > m_e + THR_LOG2)) {                                       \
        float mn = fmaxf(m_e, mx);                                            \
        float sc = fexp2(m_e - mn);                                           \
        m_e = mn;                                                             \
        ls_e *= sc;                                                           \
        float scr[4];                                                         \
        _Pragma("unroll") for (int r = 0; r < 4; ++r) scr[r] = __shfl(sc, g * 4 + r); \
        _Pragma("unroll") for (int ff = 0; ff < 8; ++ff)                      \
          _Pragma("unroll") for (int r = 0; r < 4; ++r) O[e][ff][r] *= scr[r]; \
      }                                                                       \
      float p[4][4];                                                          \
      float ssum[4];                                                          \
      _Pragma("unroll") for (int sf = 0; sf < 4; ++sf) {                      \
        _Pragma("unroll") for (int r = 0; r < 4; ++r)                         \
          p[sf][r] = fexp2(sa[e][sf][r] - m_e);                               \
        ssum[sf] = (p[sf][0] + p[sf][1]) + (p[sf][2] + p[sf][3]);             \
      }                                                                       \
      float sum = (ssum[0] + ssum[1]) + (ssum[2] + ssum[3]);                  \
      sum += __shfl_xor(sum, 16);                                             \
      sum += __shfl_xor(sum, 32);                                             \
      ls_e += sum;                                                            \
      paf[e][0] = (bf16x8){(__bf16)p[0][0], (__bf16)p[0][1], (__bf16)p[0][2], (__bf16)p[0][3], \
                           (__bf16)p[1][0], (__bf16)p[1][1], (__bf16)p[1][2], (__bf16)p[1][3]}; \
      paf[e][1] = (bf16x8){(__bf16)p[2][0], (__bf16)p[2][1], (__bf16)p[2][2], (__bf16)p[2][3], \
                           (__bf16)p[3][0], (__bf16)p[3][1], (__bf16)p[3][2], (__bf16)p[3][3]}; \
    }                                                                         \
    __builtin_amdgcn_s_setprio(1);                                            \
    bf16x8 vv1[8];                                                            \
    _Pragma("unroll") for (int f = 0; f < 8; ++f)                             \
      vv1[f] = *(const bf16x8*)&smem[(vOff) + kb1 + f * 1024];                \
    _Pragma("unroll") for (int f = 0; f < 8; ++f) {                           \
      O[0][f] = mfma16(paf[0][0], vv0[f], O[0][f]);                           \
      O[1][f] = mfma16(paf[1][0], vv0[f], O[1][f]);                           \
    }                                                                         \
    _Pragma("unroll") for (int f = 0; f < 8; ++f) {                           \
      O[0][f] = mfma16(paf[0][1], vv1[f], O[0][f]);                           \
      O[1][f] = mfma16(paf[1][1], vv1[f], O[1][f]);                           \
    }                                                                         \
    __builtin_amdgcn_s_setprio(0);                                            \
  } while (0)

  STAGE2(0, 4096, 16384, 24576, 0);

#pragma unroll 1
  for (int t = 0; t < 16; t += 2) {
    __syncthreads();  // pair A (slots 0,1) staged; all waves done with pair B
    STAGE2(8192, 12288, 32768, 40960, (t + 1) * 128);
    TILE(0, 16384);
    TILE(4096, 24576);
    __syncthreads();  // pair B (slots 2,3) staged; all waves done with pair A
    if (t < 14) STAGE2(0, 4096, 16384, 24576, (t + 2) * 128);
    TILE(8192, 32768);
    TILE(12288, 40960);
  }

  // epilogue: redistribute 1/ls from c-layout to (g,r)-layout
  float inv0 = 1.f / ls0, inv1 = 1.f / ls1;
  float i0[4], i1[4];
#pragma unroll
  for (int r = 0; r < 4; ++r) {
    i0[r] = __shfl(inv0, g * 4 + r);
    i1[r] = __shfl(inv1, g * 4 + r);
  }
  float res[8][4];
  float ss[4] = {0.f, 0.f, 0.f, 0.f};
#pragma unroll
  for (int f = 0; f < 8; ++f)
#pragma unroll
    for (int r = 0; r < 4; ++r) {
      float vv = O[0][f][r] * i0[r] - lambda_full * (O[1][f][r] * i1[r]);
      res[f][r] = vv;
      ss[r] += vv * vv;
    }
#pragma unroll
  for (int off = 1; off < 16; off <<= 1)
#pragma unroll
    for (int r = 0; r < 4; ++r) ss[r] += __shfl_xor(ss[r], off);
  float rms[4];
#pragma unroll
  for (int r = 0; r < 4; ++r)
    rms[r] = rsqrtf(ss[r] * (1.0f / 128.0f) + 1e-5f) * ONE_MINUS_LI;
  float w[8];
#pragma unroll
  for (int f = 0; f < 8; ++f) w[f] = subln[f * 16 + c];
#pragma unroll
  for (int f = 0; f < 8; ++f)
#pragma unroll
    for (int r = 0; r < 4; ++r)
      AO[(size_t)(t0 + g * 4 + r) * 2048 + h * 128 + f * 16 + c] = f2b(res[f][r] * rms[r] * w[f]);
}

// ------------------------------------------------------------------------------
extern "C" void kernel_launch(void* const* d_in, const int* in_sizes, int n_in,
                              void* d_out, int out_size, void* d_ws, size_t ws_size,
                              hipStream_t stream) {
  const float* q     = (const float*)d_in[0];
  const float* k     = (const float*)d_in[1];
  const float* v     = (const float*)d_in[2];
  const float* Wq    = (const float*)d_in[3];
  const float* Wk    = (const float*)d_in[4];
  const float* Wv    = (const float*)d_in[5];
  const float* Wout  = (const float*)d_in[6];
  const float* lq1   = (const float*)d_in[7];
  const float* lk1   = (const float*)d_in[8];
  const float* lq2   = (const float*)d_in[9];
  const float* lk2   = (const float*)d_in[10];
  const float* subln = (const float*)d_in[11];
  float* out = (float*)d_out;

  char* ws = (char*)d_ws;
  size_t off = 0;
  auto alloc = [&](size_t bytes) -> void* {
    void* p = ws + off;
    off += (bytes + 255) & ~(size_t)255;
    return p;
  };
  u16* qb  = (u16*)alloc(2048ull * 2048 * 2);
  u16* kb  = (u16*)alloc(2048ull * 2048 * 2);
  u16* vb  = (u16*)alloc(2048ull * 2048 * 2);
  u16* WqT = (u16*)alloc(2048ull * 2048 * 2);
  u16* WkT = (u16*)alloc(1024ull * 2048 * 2);
  u16* WvT = (u16*)alloc(1024ull * 2048 * 2);
  u16* WoT = (u16*)alloc(2048ull * 2048 * 2);
  f32x2* tbl = (f32x2*)alloc(2048ull * 32 * 8);
  u16* Qh  = (u16*)alloc(32ull * 2048 * 64 * 2);
  u16* Kh  = (u16*)alloc(16ull * 2048 * 64 * 2);
  u16* Vt  = (u16*)alloc(1024ull * 2048 * 2);
  u16* AO  = (u16*)alloc(2048ull * 2048 * 2);

  // 1. fused prep: cast q/k/v + rope table + all weight transposes (one launch)
  prep_kernel<<<18688, 256, 0, stream>>>(q, k, v, qb, kb, vb, tbl,
                                         Wq, WqT, Wk, WkT, Wv, WvT, Wout, WoT);
  // 2. projections + fused RoPE (Q,K) + fused permuted V-transpose (one launch)
  gemm_qkv_kernel<<<512, 256, 0, stream>>>(qb, WqT, Qh, kb, WkT, Kh, vb, WvT, Vt, tbl);
  // 3. differential flash attention -> AO bf16 [2048][2048]
  attn_kernel<<<256, 512, 0, stream>>>(Qh, Kh, Vt, AO, lq1, lk1, lq2, lk2, subln);
  // 4. output projection -> f32 d_out (128x64 tiles, 2 blocks/CU)
  gemm_one_kernel<<<512, 256, 0, stream>>>(AO, WoT, out);
}

// Round 13
// 140.370 us; speedup vs baseline: 1.1329x; 1.0033x over previous
//
#include <hip/hip_runtime.h>

typedef unsigned short u16;
typedef unsigned int u32;
typedef float f32x4 __attribute__((ext_vector_type(4)));
typedef float f32x2 __attribute__((ext_vector_type(2)));
typedef unsigned int u32x2 __attribute__((ext_vector_type(2)));
typedef __bf16 bf16x8 __attribute__((ext_vector_type(8)));
typedef __bf16 bf16x4 __attribute__((ext_vector_type(4)));

#define LAMBDA_INIT_F 0.7836057665316245f
#define ONE_MINUS_LI  0.2163942334683755f
#define THR_LOG2 11.0f
// 0.125 * log2(e): fold softmax base-2 conversion into Q scaling
#define Q_SCALE 0.18033688011112042f

__device__ __forceinline__ u16 f2b(float f) {
  union { float f; u32 u; } x; x.f = f;
  u32 r = x.u + 0x7fffu + ((x.u >> 16) & 1u);
  return (u16)(r >> 16);
}

__device__ __forceinline__ f32x4 mfma16(bf16x8 a, bf16x8 b, f32x4 c) {
  return __builtin_amdgcn_mfma_f32_16x16x32_bf16(a, b, c, 0, 0, 0);
}

__device__ __forceinline__ float fexp2(float x) { return __builtin_amdgcn_exp2f(x); }
__device__ __forceinline__ float max3(float a, float b, float c) {
  return fmaxf(fmaxf(a, b), c);  // clang fuses to v_max3_f32
}

// async global->LDS, 16B per lane; LDS dest must be linear in lane order
__device__ __forceinline__ void gll16(const void* gp, void* lp) {
  __builtin_amdgcn_global_load_lds((__attribute__((address_space(1))) void*)(gp),
                                   (__attribute__((address_space(3))) void*)(lp),
                                   16, 0, 0);
}

// ------------- tiled transpose+cast body: f32 [R][C] -> bf16 [C][R] -----------
__device__ __forceinline__ void trans_body2(const float* __restrict__ in,
                                            u16* __restrict__ out, int R, int C,
                                            int bxb, int byb) {
  __shared__ float tile[32][33];
  int bx = bxb * 32;  // col base
  int by = byb * 32;  // row base
  int tx = threadIdx.x & 31, ty = threadIdx.x >> 5;
#pragma unroll
  for (int i = 0; i < 32; i += 8)
    tile[ty + i][tx] = in[(size_t)(by + ty + i) * C + bx + tx];
  __syncthreads();
#pragma unroll
  for (int i = 0; i < 32; i += 8)
    out[(size_t)(bx + ty + i) * R + by + tx] = f2b(tile[tx][ty + i]);
}

// --- fused prep: cast q/k/v -> bf16, rope cos/sin table, 4 weight transposes --
// grid 1D: [0,6144) cast, [6144,6400) table, [6400,18688) wtrans
__global__ __launch_bounds__(256) void prep_kernel(
    const float* __restrict__ q, const float* __restrict__ k, const float* __restrict__ v,
    u16* __restrict__ qb, u16* __restrict__ kb, u16* __restrict__ vb,
    f32x2* __restrict__ tbl,
    const float* __restrict__ Wq, u16* __restrict__ WqT,
    const float* __restrict__ Wk, u16* __restrict__ WkT,
    const float* __restrict__ Wv, u16* __restrict__ WvT,
    const float* __restrict__ Wo, u16* __restrict__ WoT) {
  int bid = blockIdx.x;
  if (bid < 6144) {
    int seg = bid >> 11;
    int i = (bid & 2047) * 256 + threadIdx.x;
    const float* in = seg == 0 ? q : (seg == 1 ? k : v);
    u16* out = seg == 0 ? qb : (seg == 1 ? kb : vb);
    const f32x4* p = (const f32x4*)(in + (size_t)i * 8);
    f32x4 a = p[0], b = p[1];
    union { u16 u[8]; f32x4 v; } o;
#pragma unroll
    for (int j = 0; j < 4; ++j) { o.u[j] = f2b(a[j]); o.u[4 + j] = f2b(b[j]); }
    *(f32x4*)(out + (size_t)i * 8) = o.v;
    return;
  }
  if (bid < 6400) {
    int idx = (bid - 6144) * 256 + threadIdx.x;  // t*32 + j
    int t = idx >> 5, j = idx & 31;
    float theta = (float)j * (1.0f / 32.0f);
    float denom = expf(theta * 9.210340371976184f);  // 10000^theta
    float invf = 1.0f / (denom + 1e-8f);
    float ang = (float)t * invf;
    tbl[idx] = (f32x2){cosf(ang), sinf(ang)};
    return;
  }
  int w = bid - 6400;
  if (w < 4096)      trans_body2(Wq, WqT, 2048, 2048, w & 63, w >> 6);
  else if (w < 6144) { w -= 4096; trans_body2(Wk, WkT, 2048, 1024, w & 31, w >> 5); }
  else if (w < 8192) { w -= 6144; trans_body2(Wv, WvT, 2048, 1024, w & 31, w >> 5); }
  else               { w -= 8192; trans_body2(Wo, WoT, 2048, 2048, w & 63, w >> 6); }
}

// ---------------- GEMM body: 128x128 tile, BK=64, fused epilogues -------------
// Prefetch-double-buffered (attn/m97 T3-minimum skeleton).
// smem layout (u16 elems): As0@0 Bs0@8192 As1@16384 Bs1@24576 (64KB total).
// MODE 0: plain f32 C[M][N]
// MODE 1: RoPE epilogue -> bf16 head-major Oh[ncol>>6][t][64]. Lane pair (c,c^1)
//         handles one column pair: even lane rows 0-1, odd lane rows 2-3.
// MODE 2: V permuted transpose -> bf16 Vt[dv][2048]; within each 32-key block
//         position p = 8g + 4(i&1) + r (r-contiguous -> one 8B store per quad).
template <int MODE>
__device__ __forceinline__ void gemm_body(u16* smem,
                                          const u16* __restrict__ A,
                                          const u16* __restrict__ Bt,
                                          void* __restrict__ Cout,
                                          const f32x2* __restrict__ tbl,
                                          float scale,
                                          int N, int K, int bx, int by) {
  const int tid = threadIdx.x;
  const int lane = tid & 63;
  const int wave = tid >> 6;
  const int m0 = by * 128;
  const int n0 = bx * 128;
  const int wm = (wave >> 1) * 64;
  const int wn = (wave & 1) * 64;
  const int g = lane >> 4, c = lane & 15;

  f32x4 acc[4][4];
#pragma unroll
  for (int i = 0; i < 4; ++i)
#pragma unroll
    for (int j = 0; j < 4; ++j) acc[i][j] = (f32x4){0.f, 0.f, 0.f, 0.f};

#define GSTAGE(aOff, bOff, k0)                                                  \
  do {                                                                          \
    _Pragma("unroll") for (int it = 0; it < 4; ++it) {                          \
      int gi = it * 256 + tid;                                                  \
      int R = gi >> 3;                                                          \
      int lg = (gi & 7) ^ (R & 7);                                              \
      gll16(A + (size_t)(m0 + R) * K + (k0) + lg * 8, smem + (aOff) + gi * 8);  \
      gll16(Bt + (size_t)(n0 + R) * K + (k0) + lg * 8, smem + (bOff) + gi * 8); \
    }                                                                           \
  } while (0)

#define GCOMP(aOff, bOff)                                                       \
  do {                                                                          \
    _Pragma("unroll") for (int kk = 0; kk < 2; ++kk) {                          \
      bf16x8 af[4], bf[4];                                                      \
      _Pragma("unroll") for (int i = 0; i < 4; ++i) {                           \
        int ph = ((kk * 4 + g) ^ (c & 7)) * 8;                                  \
        af[i] = *(const bf16x8*)&smem[(aOff) + (wm + i * 16 + c) * 64 + ph];    \
        bf[i] = *(const bf16x8*)&smem[(bOff) + (wn + i * 16 + c) * 64 + ph];    \
      }                                                                         \
      _Pragma("unroll") for (int i = 0; i < 4; ++i)                             \
        _Pragma("unroll") for (int j = 0; j < 4; ++j)                           \
          acc[i][j] = mfma16(af[i], bf[j], acc[i][j]);                          \
    }                                                                           \
  } while (0)

  const int NT = K / 64;
  GSTAGE(0, 8192, 0);
#pragma unroll 1
  for (int t = 0; t < NT; t += 2) {
    __syncthreads();  // buf0 staged (issued a full phase ago); buf1 consumed
    GSTAGE(16384, 24576, (t + 1) * 64);
    GCOMP(0, 8192);
    __syncthreads();  // buf1 staged; buf0 consumed
    if (t + 2 < NT) GSTAGE(0, 8192, (t + 2) * 64);
    GCOMP(16384, 24576);
  }
#undef GSTAGE
#undef GCOMP

  if constexpr (MODE == 0) {
    float* C = (float*)Cout;
#pragma unroll
    for (int i = 0; i < 4; ++i)
#pragma unroll
      for (int j = 0; j < 4; ++j) {
        int mrow = m0 + wm + i * 16 + g * 4;
        int ncol = n0 + wn + j * 16 + c;
#pragma unroll
        for (int r = 0; r < 4; ++r) C[(size_t)(mrow + r) * N + ncol] = acc[i][j][r];
      }
  } else if constexpr (MODE == 1) {
    u16* Oh = (u16*)Cout;
    const bool even = (c & 1) == 0;
    const int rbase = (c & 1) * 2;  // even lane rows 0-1, odd lane rows 2-3
#pragma unroll
    for (int i = 0; i < 4; ++i)
#pragma unroll
      for (int j = 0; j < 4; ++j) {
        int mrow = m0 + wm + i * 16 + g * 4;
        int ncol = n0 + wn + j * 16 + c;
        int hh = ncol >> 6;
        int d = ncol & 63;
        int jd = d >> 1;        // same for both parities (d even / d odd pair)
        int dst = d & ~1;       // column-pair base
        f32x4 own = acc[i][j];
        f32x4 part;
#pragma unroll
        for (int r = 0; r < 4; ++r) part[r] = __shfl_xor(own[r], 1);
#pragma unroll
        for (int rr = 0; rr < 2; ++rr) {
          int r = rbase + rr;
          float x1 = even ? own[r] : part[r];  // value at even col of pair
          float x2 = even ? part[r] : own[r];  // value at odd col of pair
          f32x2 cs = tbl[(mrow + r) * 32 + jd];
          float o1 = (x1 * cs[0] - x2 * cs[1]) * scale;
          float o2 = (x1 * cs[1] + x2 * cs[0]) * scale;
          u32 pk = (u32)f2b(o1) | ((u32)f2b(o2) << 16);
          *(u32*)&Oh[((size_t)hh * 2048 + mrow + r) * 64 + dst] = pk;
        }
      }
  } else {
    u16* Vt = (u16*)Cout;
#pragma unroll
    for (int i = 0; i < 4; ++i)
#pragma unroll
      for (int j = 0; j < 4; ++j) {
        int ncol = n0 + wn + j * 16 + c;              // dv
        int tblk = (m0 + wm + i * 16) >> 5;           // 32-key block
        int p0 = 8 * g + 4 * (i & 1);                 // permuted base, +r contiguous
        u32x2 pk;
        pk[0] = (u32)f2b(acc[i][j][0]) | ((u32)f2b(acc[i][j][1]) << 16);
        pk[1] = (u32)f2b(acc[i][j][2]) | ((u32)f2b(acc[i][j][3]) << 16);
        *(u32x2*)&Vt[(size_t)ncol * 2048 + tblk * 32 + p0] = pk;
      }
  }
}

// ------- GEMM body: 128x64 tile, BK=64, prefetch-dbuf, plain f32 epilogue -----
// smem layout (u16 elems): As0@0 Bs0@8192 As1@12288 Bs1@20480 (48KB total).
__device__ __forceinline__ void gemm_body64(u16* smem,
                                            const u16* __restrict__ A,
                                            const u16* __restrict__ Bt,
                                            float* __restrict__ C,
                                            int N, int K, int bx, int by) {
  const int tid = threadIdx.x;
  const int lane = tid & 63;
  const int wave = tid >> 6;
  const int m0 = by * 128;
  const int n0 = bx * 64;
  const int wm = (wave >> 1) * 64;
  const int wn = (wave & 1) * 32;
  const int g = lane >> 4, c = lane & 15;

  f32x4 acc[4][2];
#pragma unroll
  for (int i = 0; i < 4; ++i)
#pragma unroll
    for (int j = 0; j < 2; ++j) acc[i][j] = (f32x4){0.f, 0.f, 0.f, 0.f};

#define G64STAGE(aOff, bOff, k0)                                                \
  do {                                                                          \
    _Pragma("unroll") for (int it = 0; it < 4; ++it) {                          \
      int gi = it * 256 + tid;                                                  \
      int R = gi >> 3;                                                          \
      int lg = (gi & 7) ^ (R & 7);                                              \
      gll16(A + (size_t)(m0 + R) * K + (k0) + lg * 8, smem + (aOff) + gi * 8);  \
    }                                                                           \
    _Pragma("unroll") for (int it = 0; it < 2; ++it) {                          \
      int gi = it * 256 + tid;                                                  \
      int R = gi >> 3;                                                          \
      int lg = (gi & 7) ^ (R & 7);                                              \
      gll16(Bt + (size_t)(n0 + R) * K + (k0) + lg * 8, smem + (bOff) + gi * 8); \
    }                                                                           \
  } while (0)

#define G64COMP(aOff, bOff)                                                     \
  do {                                                                          \
    _Pragma("unroll") for (int kk = 0; kk < 2; ++kk) {                          \
      bf16x8 af[4], bf[2];                                                      \
      int ph = ((kk * 4 + g) ^ (c & 7)) * 8;                                    \
      _Pragma("unroll") for (int i = 0; i < 4; ++i)                             \
        af[i] = *(const bf16x8*)&smem[(aOff) + (wm + i * 16 + c) * 64 + ph];    \
      _Pragma("unroll") for (int j = 0; j < 2; ++j)                             \
        bf[j] = *(const bf16x8*)&smem[(bOff) + (wn + j * 16 + c) * 64 + ph];    \
      _Pragma("unroll") for (int i = 0; i < 4; ++i)                             \
        _Pragma("unroll") for (int j = 0; j < 2; ++j)                           \
          acc[i][j] = mfma16(af[i], bf[j], acc[i][j]);                          \
    }                                                                           \
  } while (0)

  const int NT = K / 64;
  G64STAGE(0, 8192, 0);
#pragma unroll 1
  for (int t = 0; t < NT; t += 2) {
    __syncthreads();
    G64STAGE(12288, 20480, (t + 1) * 64);
    G64COMP(0, 8192);
    __syncthreads();
    if (t + 2 < NT) G64STAGE(0, 8192, (t + 2) * 64);
    G64COMP(12288, 20480);
  }
#undef G64STAGE
#undef G64COMP

#pragma unroll
  for (int i = 0; i < 4; ++i)
#pragma unroll
    for (int j = 0; j < 2; ++j) {
      int mrow = m0 + wm + i * 16 + g * 4;
      int ncol = n0 + wn + j * 16 + c;
#pragma unroll
      for (int r = 0; r < 4; ++r) C[(size_t)(mrow + r) * N + ncol] = acc[i][j][r];
    }
}

// fused q/k/v projections + RoPE + V-transpose epilogues: 512 blocks (2/CU)
__global__ __launch_bounds__(256, 2) void gemm_qkv_kernel(
    const u16* __restrict__ qb, const u16* __restrict__ WqT, u16* __restrict__ Qh,
    const u16* __restrict__ kb, const u16* __restrict__ WkT, u16* __restrict__ Kh,
    const u16* __restrict__ vb, const u16* __restrict__ WvT, u16* __restrict__ Vt,
    const f32x2* __restrict__ tbl) {
  __shared__ u16 smem[32768];  // 64KB: As0/Bs0/As1/Bs1
  // XCD-aware swizzle: 512 blocks, 64 consecutive work-ids per XCD
  int bid = ((blockIdx.x & 7) << 6) | (blockIdx.x >> 3);
  if (bid < 256) {
    gemm_body<1>(smem, qb, WqT, Qh, tbl, Q_SCALE, 2048, 2048, bid & 15, bid >> 4);
  } else if (bid < 384) {
    int t = bid - 256;
    gemm_body<1>(smem, kb, WkT, Kh, tbl, 1.0f, 1024, 2048, t & 7, t >> 3);
  } else {
    int t = bid - 384;
    gemm_body<2>(smem, vb, WvT, Vt, tbl, 1.0f, 1024, 2048, t & 7, t >> 3);
  }
}

// out-projection: 128x64 tiles -> 512 blocks (2 blocks/CU)
__global__ __launch_bounds__(256, 2) void gemm_one_kernel(const u16* __restrict__ A,
                                                          const u16* __restrict__ Bt,
                                                          float* __restrict__ C) {
  __shared__ u16 smem[24576];  // 48KB
  int bid = ((blockIdx.x & 7) << 6) | (blockIdx.x >> 3);  // 512 blocks
  gemm_body64(smem, A, Bt, C, 2048, 2048, bid & 31, bid >> 5);
}

// ---------------- fused differential flash attention --------------------------
// R12 math with tile-pair pipelining: QK(A); QK(B); SM+PV(A); SM+PV(B) per
// mega-phase — SM(B)'s VALU is independent of PV(A)'s MFMAs within the same
// straight-line region, letting the scheduler dual-flow the two pipes (m114).
// All layout math identical to R12 (proven); pure source reordering.
__global__ __launch_bounds__(512, 2) void attn_kernel(const u16* __restrict__ Qb,
                                                      const u16* __restrict__ Kb,
                                                      const u16* __restrict__ Vt,
                                                      u16* __restrict__ AO,
                                                      const float* __restrict__ lq1,
                                                      const float* __restrict__ lk1,
                                                      const float* __restrict__ lq2,
                                                      const float* __restrict__ lk2,
                                                      const float* __restrict__ subln) {
  // XCD swizzle: 32 consecutive work-ids (2 heads) per XCD's L2
  const int b = ((blockIdx.x & 7) << 5) | (blockIdx.x >> 3);
  const int h = b >> 4;
  const int tid = threadIdx.x;
  const int wave = tid >> 6;
  const int lane = tid & 63;
  const int t0 = ((b & 15) * 8 + wave) * 16;
  const int g = lane >> 4, c = lane & 15;
  const int c7 = c & 7;

  __shared__ u16 smem[49152];  // 96KB: K slots 0/4096/8192/12288, V 16384/24576/32768/40960

  const u16* Kh = Kb + (size_t)h * 2048 * 64;
  const u16* Vh = Vt + (size_t)(h >> 1) * 128 * 2048;

  // lambda (wave-parallel)
  float myl1 = lq1[lane] * lk1[lane];
  float myl2 = lq2[lane] * lk2[lane];
#pragma unroll
  for (int off = 32; off; off >>= 1) {
    myl1 += __shfl_xor(myl1, off);
    myl2 += __shfl_xor(myl2, off);
  }
  const float lambda_full = expf(myl1) - expf(myl2) + LAMBDA_INIT_F;

  // Q fragments (B-operand: col = q-row = c, natural d-slots)
  bf16x8 qf[2][2];
#pragma unroll
  for (int e = 0; e < 2; ++e)
#pragma unroll
    for (int d = 0; d < 2; ++d)
      qf[e][d] = *(const bf16x8*)(Qb + ((size_t)(2 * h + e) * 2048 + t0 + c) * 64 + d * 32 + g * 8);

  // loop-invariant LDS read bases (u16-elem units); shared by K and V reads
  const int kb0 = c * 64 + ((g ^ c7) * 8);
  const int kb1 = kb0 ^ 32;

  // per-thread stage source bases (granule-XOR pre-swizzled)
  const u16* ksrc0;
  const u16* vsrc0;
  const u16* vsrc1;
  { int gi = tid;       int R = gi >> 3; ksrc0 = Kh + R * 64 + ((gi & 7) ^ (R & 7)) * 8; }
  { int gi = tid;       int R = gi >> 3; vsrc0 = Vh + (size_t)R * 2048 + ((gi & 7) ^ (R & 7)) * 8; }
  { int gi = 512 + tid; int R = gi >> 3; vsrc1 = Vh + (size_t)R * 2048 + ((gi & 7) ^ (R & 7)) * 8; }

  f32x4 O[2][8];
#pragma unroll
  for (int e = 0; e < 2; ++e)
#pragma unroll
    for (int f = 0; f < 8; ++f) O[e][f] = (f32x4){0.f, 0.f, 0.f, 0.f};
  float m0 = -1e30f, m1 = -1e30f, ls0 = 0.f, ls1 = 0.f;

  f32x4 saA[2][4], saB[2][4];

// stage 128 keys (2 tiles) into slot pair (kOffA/kOffB, vOffA/vOffB)
#define STAGE2(kOffA, kOffB, vOffA, vOffB, s0)                          \
  do {                                                                  \
    gll16(ksrc0 + (size_t)(s0) * 64, smem + (kOffA) + tid * 8);         \
    gll16(ksrc0 + (size_t)((s0) + 64) * 64, smem + (kOffB) + tid * 8);  \
    gll16(vsrc0 + (s0), smem + (vOffA) + tid * 8);                      \
    gll16(vsrc1 + (s0), smem + (vOffA) + 4096 + tid * 8);               \
    gll16(vsrc0 + (s0) + 64, smem + (vOffB) + tid * 8);                 \
    gll16(vsrc1 + (s0) + 64, smem + (vOffB) + 4096 + tid * 8);          \
  } while (0)

// QK^T for one 64-key tile -> sa (both sub-heads)
#define TILE_QK(kOff, sa)                                                     \
  do {                                                                        \
    bf16x8 kf[4][2];                                                          \
    _Pragma("unroll") for (int sf = 0; sf < 4; ++sf) {                        \
      kf[sf][0] = *(const bf16x8*)&smem[(kOff) + kb0 + sf * 1024];            \
      kf[sf][1] = *(const bf16x8*)&smem[(kOff) + kb1 + sf * 1024];            \
    }                                                                         \
    _Pragma("unroll") for (int e = 0; e < 2; ++e)                             \
      _Pragma("unroll") for (int sf = 0; sf < 4; ++sf) {                      \
        f32x4 z = (f32x4){0.f, 0.f, 0.f, 0.f};                                \
        z = mfma16(kf[sf][0], qf[e][0], z);                                   \
        z = mfma16(kf[sf][1], qf[e][1], z);                                   \
        sa[e][sf] = z;                                                        \
      }                                                                       \
  } while (0)

// softmax + PV for one 64-key tile (consumes sa)
#define TILE_SMPV(vOff, sa)                                                   \
  do {                                                                        \
    bf16x8 vv0[8];                                                            \
    _Pragma("unroll") for (int f = 0; f < 8; ++f)                             \
      vv0[f] = *(const bf16x8*)&smem[(vOff) + kb0 + f * 1024];                \
    bf16x8 paf[2][2];                                                         \
    _Pragma("unroll") for (int e = 0; e < 2; ++e) {                           \
      float& m_e = e ? m1 : m0;                                               \
      float& ls_e = e ? ls1 : ls0;                                            \
      float t1 = max3(sa[e][0][0], sa[e][0][1], sa[e][0][2]);                 \
      float t2 = max3(sa[e][0][3], sa[e][1][0], sa[e][1][1]);                 \
      float t3 = max3(sa[e][1][2], sa[e][1][3], sa[e][2][0]);                 \
      float t4 = max3(sa[e][2][1], sa[e][2][2], sa[e][2][3]);                 \
      float t5 = max3(sa[e][3][0], sa[e][3][1], sa[e][3][2]);                 \
      float mx = max3(t1, t2, t3);                                            \
      mx = max3(mx, t4, t5);                                                  \
      mx = fmaxf(mx, sa[e][3][3]);                                            \
      mx = fmaxf(mx, __shfl_xor(mx, 16));                                     \
      mx = fmaxf(mx, __shfl_xor(mx, 32));                                     \
      if (__any(mx > m_e + THR_LOG2)) {                                       \
        float mn = fmaxf(m_e, mx);                                            \
        float sc = fexp2(m_e - mn);                                           \
        m_e = mn;                                                             \
        ls_e *= sc;                                                           \
        float scr[4];                                                         \
        _Pragma("unroll") for (int r = 0; r < 4; ++r) scr[r] = __shfl(sc, g * 4 + r); \
        _Pragma("unroll") for (int ff = 0; ff < 8; ++ff)                      \
          _Pragma("unroll") for (int r = 0; r < 4; ++r) O[e][ff][r] *= scr[r]; \
      }                                                                       \
      float p[4][4];                                                          \
      float ssum[4];                                                          \
      _Pragma("unroll") for (int sf = 0; sf < 4; ++sf) {                      \
        _Pragma("unroll") for (int r = 0; r < 4; ++r)                         \
          p[sf][r] = fexp2(sa[e][sf][r] - m_e);                               \
        ssum[sf] = (p[sf][0] + p[sf][1]) + (p[sf][2] + p[sf][3]);             \
      }                                                                       \
      float sum = (ssum[0] + ssum[1]) + (ssum[2] + ssum[3]);                  \
      sum += __shfl_xor(sum, 16);                                             \
      sum += __shfl_xor(sum, 32);                                             \
      ls_e += sum;                                                            \
      paf[e][0] = (bf16x8){(__bf16)p[0][0], (__bf16)p[0][1], (__bf16)p[0][2], (__bf16)p[0][3], \
                           (__bf16)p[1][0], (__bf16)p[1][1], (__bf16)p[1][2], (__bf16)p[1][3]}; \
      paf[e][1] = (bf16x8){(__bf16)p[2][0], (__bf16)p[2][1], (__bf16)p[2][2], (__bf16)p[2][3], \
                           (__bf16)p[3][0], (__bf16)p[3][1], (__bf16)p[3][2], (__bf16)p[3][3]}; \
    }                                                                         \
    __builtin_amdgcn_s_setprio(1);                                            \
    bf16x8 vv1[8];                                                            \
    _Pragma("unroll") for (int f = 0; f < 8; ++f)                             \
      vv1[f] = *(const bf16x8*)&smem[(vOff) + kb1 + f * 1024];                \
    _Pragma("unroll") for (int f = 0; f < 8; ++f) {                           \
      O[0][f] = mfma16(paf[0][0], vv0[f], O[0][f]);                           \
      O[1][f] = mfma16(paf[1][0], vv0[f], O[1][f]);                           \
    }                                                                         \
    _Pragma("unroll") for (int f = 0; f < 8; ++f) {                           \
      O[0][f] = mfma16(paf[0][1], vv1[f], O[0][f]);                           \
      O[1][f] = mfma16(paf[1][1], vv1[f], O[1][f]);                           \
    }                                                                         \
    __builtin_amdgcn_s_setprio(0);                                            \
  } while (0)

  STAGE2(0, 4096, 16384, 24576, 0);

#pragma unroll 1
  for (int t = 0; t < 16; t += 2) {
    __syncthreads();  // pair A (slots 0,1) staged; all waves done with pair B
    STAGE2(8192, 12288, 32768, 40960, (t + 1) * 128);
    TILE_QK(0, saA);
    TILE_QK(4096, saB);
    TILE_SMPV(16384, saA);
    TILE_SMPV(24576, saB);
    __syncthreads();  // pair B (slots 2,3) staged; all waves done with pair A
    if (t < 14) STAGE2(0, 4096, 16384, 24576, (t + 2) * 128);
    TILE_QK(8192, saA);
    TILE_QK(12288, saB);
    TILE_SMPV(32768, saA);
    TILE_SMPV(40960, saB);
  }

  // epilogue: redistribute 1/ls from c-layout to (g,r)-layout
  float inv0 = 1.f / ls0, inv1 = 1.f / ls1;
  float i0[4], i1[4];
#pragma unroll
  for (int r = 0; r < 4; ++r) {
    i0[r] = __shfl(inv0, g * 4 + r);
    i1[r] = __shfl(inv1, g * 4 + r);
  }
  float res[8][4];
  float ss[4] = {0.f, 0.f, 0.f, 0.f};
#pragma unroll
  for (int f = 0; f < 8; ++f)
#pragma unroll
    for (int r = 0; r < 4; ++r) {
      float vv = O[0][f][r] * i0[r] - lambda_full * (O[1][f][r] * i1[r]);
      res[f][r] = vv;
      ss[r] += vv * vv;
    }
#pragma unroll
  for (int off = 1; off < 16; off <<= 1)
#pragma unroll
    for (int r = 0; r < 4; ++r) ss[r] += __shfl_xor(ss[r], off);
  float rms[4];
#pragma unroll
  for (int r = 0; r < 4; ++r)
    rms[r] = rsqrtf(ss[r] * (1.0f / 128.0f) + 1e-5f) * ONE_MINUS_LI;
  float w[8];
#pragma unroll
  for (int f = 0; f < 8; ++f) w[f] = subln[f * 16 + c];
#pragma unroll
  for (int f = 0; f < 8; ++f)
#pragma unroll
    for (int r = 0; r < 4; ++r)
      AO[(size_t)(t0 + g * 4 + r) * 2048 + h * 128 + f * 16 + c] = f2b(res[f][r] * rms[r] * w[f]);
}

// ------------------------------------------------------------------------------
extern "C" void kernel_launch(void* const* d_in, const int* in_sizes, int n_in,
                              void* d_out, int out_size, void* d_ws, size_t ws_size,
                              hipStream_t stream) {
  const float* q     = (const float*)d_in[0];
  const float* k     = (const float*)d_in[1];
  const float* v     = (const float*)d_in[2];
  const float* Wq    = (const float*)d_in[3];
  const float* Wk    = (const float*)d_in[4];
  const float* Wv    = (const float*)d_in[5];
  const float* Wout  = (const float*)d_in[6];
  const float* lq1   = (const float*)d_in[7];
  const float* lk1   = (const float*)d_in[8];
  const float* lq2   = (const float*)d_in[9];
  const float* lk2   = (const float*)d_in[10];
  const float* subln = (const float*)d_in[11];
  float* out = (float*)d_out;

  char* ws = (char*)d_ws;
  size_t off = 0;
  auto alloc = [&](size_t bytes) -> void* {
    void* p = ws + off;
    off += (bytes + 255) & ~(size_t)255;
    return p;
  };
  u16* qb  = (u16*)alloc(2048ull * 2048 * 2);
  u16* kb  = (u16*)alloc(2048ull * 2048 * 2);
  u16* vb  = (u16*)alloc(2048ull * 2048 * 2);
  u16* WqT = (u16*)alloc(2048ull * 2048 * 2);
  u16* WkT = (u16*)alloc(1024ull * 2048 * 2);
  u16* WvT = (u16*)alloc(1024ull * 2048 * 2);
  u16* WoT = (u16*)alloc(2048ull * 2048 * 2);
  f32x2* tbl = (f32x2*)alloc(2048ull * 32 * 8);
  u16* Qh  = (u16*)alloc(32ull * 2048 * 64 * 2);
  u16* Kh  = (u16*)alloc(16ull * 2048 * 64 * 2);
  u16* Vt  = (u16*)alloc(1024ull * 2048 * 2);
  u16* AO  = (u16*)alloc(2048ull * 2048 * 2);

  // 1. fused prep: cast q/k/v + rope table + all weight transposes (one launch)
  prep_kernel<<<18688, 256, 0, stream>>>(q, k, v, qb, kb, vb, tbl,
                                         Wq, WqT, Wk, WkT, Wv, WvT, Wout, WoT);
  // 2. projections + fused RoPE (Q,K) + fused permuted V-transpose (one launch)
  gemm_qkv_kernel<<<512, 256, 0, stream>>>(qb, WqT, Qh, kb, WkT, Kh, vb, WvT, Vt, tbl);
  // 3. differential flash attention -> AO bf16 [2048][2048]
  attn_kernel<<<256, 512, 0, stream>>>(Qh, Kh, Vt, AO, lq1, lk1, lq2, lk2, subln);
  // 4. output projection -> f32 d_out (128x64 tiles, 2 blocks/CU)
  gemm_one_kernel<<<512, 256, 0, stream>>>(AO, WoT, out);
}